// Round 1
// baseline (1530.587 us; speedup 1.0000x reference)
//
#include <hip/hip_runtime.h>

#define NEG_SLOPE 0.2f
#define H_IN 64
#define HEADS1 4

__device__ __forceinline__ float lrelu(float v) { return v > 0.f ? v : NEG_SLOPE * v; }

// float atomic max via signed/unsigned int encoding trick (monotone in both encodings)
__device__ __forceinline__ void atomicMaxFloat(float* addr, float val) {
    if (val >= 0.f) atomicMax((int*)addr, __float_as_int(val));
    else            atomicMin((unsigned int*)addr, __float_as_uint(val));
}

// ---------------------------------------------------------------------------
// init: out1 = b1 (broadcast), d_out = b2 (broadcast), emax=-inf, denom=0
// ---------------------------------------------------------------------------
__global__ __launch_bounds__(256) void init_kernel(
    float* __restrict__ out1, const float* __restrict__ b1,
    float* __restrict__ dout, const float* __restrict__ b2,
    float* __restrict__ emax1, float* __restrict__ denom1,
    float* __restrict__ emax2, float* __restrict__ denom2, int n)
{
    long long i = (long long)blockIdx.x * 256 + threadIdx.x;
    long long tot = (long long)n * 256;
    if (i >= tot) return;
    out1[i] = b1[i & 255];
    if (i < (long long)n * 64) dout[i] = b2[i & 63];
    if (i < (long long)n * 4) { emax1[i] = -INFINITY; denom1[i] = 0.f; }
    if (i < n)                { emax2[i] = -INFINITY; denom2[i] = 0.f; }
}

// ---------------------------------------------------------------------------
// layer-1 GEMM + attention logits: h1[N,256] = x[N,64] @ W1[64,256]
// a_s1[n,h] = sum_c h1[n,h,c]*att_src[h,c]   (per-wave reduce, wave==head)
// ---------------------------------------------------------------------------
#define G1_ROWS 16
__global__ __launch_bounds__(256) void gemm1_att(
    const float* __restrict__ x, const float* __restrict__ W1,
    const float* __restrict__ atts, const float* __restrict__ attd,
    float* __restrict__ h1, float* __restrict__ a_s, float* __restrict__ a_d, int n)
{
    __shared__ float w_s[64 * 256];      // 64 KB
    __shared__ float x_s[G1_ROWS * 64];  // 4 KB
    int tid = threadIdx.x;
    for (int i = tid; i < 64 * 256; i += 256) w_s[i] = W1[i];
    int row0 = blockIdx.x * G1_ROWS;
    for (int i = tid; i < G1_ROWS * 64; i += 256) {
        int r = i >> 6, k = i & 63;
        int row = row0 + r;
        x_s[i] = (row < n) ? x[(long long)row * 64 + k] : 0.f;
    }
    __syncthreads();
    float as_w = atts[tid];   // att_src1[h][c], tid = h*64+c
    float ad_w = attd[tid];
    int head = tid >> 6;
    int lane = tid & 63;
    for (int r = 0; r < G1_ROWS; ++r) {
        int row = row0 + r;
        if (row >= n) break;           // uniform across block
        float acc = 0.f;
        #pragma unroll
        for (int k = 0; k < 64; ++k)
            acc = fmaf(x_s[r * 64 + k], w_s[k * 256 + tid], acc);
        h1[(long long)row * 256 + tid] = acc;
        float s = acc * as_w, d = acc * ad_w;
        #pragma unroll
        for (int off = 32; off > 0; off >>= 1) {
            s += __shfl_down(s, off);
            d += __shfl_down(d, off);
        }
        if (lane == 0) { a_s[row * 4 + head] = s; a_d[row * 4 + head] = d; }
    }
}

// ---------------------------------------------------------------------------
// layer-2 GEMM (input = relu(out1)) + attention logits (1 head)
// ---------------------------------------------------------------------------
#define G2_ROWS 16
__global__ __launch_bounds__(256) void gemm2_att(
    const float* __restrict__ out1, const float* __restrict__ W2,
    const float* __restrict__ atts, const float* __restrict__ attd,
    float* __restrict__ h2, float* __restrict__ a_s, float* __restrict__ a_d, int n)
{
    __shared__ float w_s[256 * 64];       // 64 KB
    __shared__ float x_s[G2_ROWS * 256];  // 16 KB
    int tid = threadIdx.x;
    for (int i = tid; i < 256 * 64; i += 256) w_s[i] = W2[i];
    int row0 = blockIdx.x * G2_ROWS;
    for (int i = tid; i < G2_ROWS * 256; i += 256) {
        int r = i >> 8, k = i & 255;
        int row = row0 + r;
        float v = (row < n) ? out1[(long long)row * 256 + k] : 0.f;
        x_s[i] = v > 0.f ? v : 0.f;      // fused ReLU
    }
    __syncthreads();
    int col = tid & 63;
    int rg  = tid >> 6;                  // 4 row-groups, one wave each
    float as_w = atts[col], ad_w = attd[col];
    for (int r = rg; r < G2_ROWS; r += 4) {
        int row = row0 + r;
        if (row >= n) continue;          // wave-uniform
        float acc = 0.f;
        #pragma unroll
        for (int k = 0; k < 256; ++k)
            acc = fmaf(x_s[r * 256 + k], w_s[k * 64 + col], acc);
        h2[(long long)row * 64 + col] = acc;
        float s = acc * as_w, d = acc * ad_w;
        #pragma unroll
        for (int off = 32; off > 0; off >>= 1) {
            s += __shfl_down(s, off);
            d += __shfl_down(d, off);
        }
        if (col == 0) { a_s[row] = s; a_d[row] = d; }
    }
}

// ---------------------------------------------------------------------------
// edge passes, layer 1 (4 heads)
// ---------------------------------------------------------------------------
__global__ __launch_bounds__(256) void edge_max4(
    const int* __restrict__ src, const int* __restrict__ dst,
    const float4* __restrict__ a_s, const float4* __restrict__ a_d,
    float* __restrict__ emax, int ne)
{
    int e = blockIdx.x * 256 + threadIdx.x;
    if (e >= ne) return;
    int s = src[e], t = dst[e];
    float4 as = a_s[s], ad = a_d[t];
    atomicMaxFloat(&emax[t * 4 + 0], lrelu(as.x + ad.x));
    atomicMaxFloat(&emax[t * 4 + 1], lrelu(as.y + ad.y));
    atomicMaxFloat(&emax[t * 4 + 2], lrelu(as.z + ad.z));
    atomicMaxFloat(&emax[t * 4 + 3], lrelu(as.w + ad.w));
}

__global__ __launch_bounds__(256) void edge_denom4(
    const int* __restrict__ src, const int* __restrict__ dst,
    const float4* __restrict__ a_s, const float4* __restrict__ a_d,
    const float4* __restrict__ emax, float* __restrict__ denom, int ne)
{
    int e = blockIdx.x * 256 + threadIdx.x;
    if (e >= ne) return;
    int s = src[e], t = dst[e];
    float4 as = a_s[s], ad = a_d[t], mx = emax[t];
    atomicAdd(&denom[t * 4 + 0], expf(lrelu(as.x + ad.x) - mx.x));
    atomicAdd(&denom[t * 4 + 1], expf(lrelu(as.y + ad.y) - mx.y));
    atomicAdd(&denom[t * 4 + 2], expf(lrelu(as.z + ad.z) - mx.z));
    atomicAdd(&denom[t * 4 + 3], expf(lrelu(as.w + ad.w) - mx.w));
}

// one block handles EPB1L edges; thread t owns channel t (head = t>>6)
#define EPB4 8
__global__ __launch_bounds__(256) void edge_aggr4(
    const int* __restrict__ src, const int* __restrict__ dst,
    const float* __restrict__ a_s, const float* __restrict__ a_d,
    const float* __restrict__ emax, const float* __restrict__ denom,
    const float* __restrict__ h1, float* __restrict__ out1, int ne)
{
    int tid = threadIdx.x;
    int h = tid >> 6;
    int e0 = blockIdx.x * EPB4;
    #pragma unroll
    for (int i = 0; i < EPB4; ++i) {
        int e = e0 + i;
        if (e >= ne) return;           // uniform
        int s = src[e], t = dst[e];
        float v = lrelu(a_s[s * 4 + h] + a_d[t * 4 + h]);   // broadcast loads
        float alpha = expf(v - emax[t * 4 + h]) / denom[t * 4 + h];
        atomicAdd(&out1[(long long)t * 256 + tid], alpha * h1[(long long)s * 256 + tid]);
    }
}

// ---------------------------------------------------------------------------
// edge passes, layer 2 (1 head)
// ---------------------------------------------------------------------------
__global__ __launch_bounds__(256) void edge_max1(
    const int* __restrict__ src, const int* __restrict__ dst,
    const float* __restrict__ a_s, const float* __restrict__ a_d,
    float* __restrict__ emax, int ne)
{
    int e = blockIdx.x * 256 + threadIdx.x;
    if (e >= ne) return;
    int s = src[e], t = dst[e];
    atomicMaxFloat(&emax[t], lrelu(a_s[s] + a_d[t]));
}

__global__ __launch_bounds__(256) void edge_denom1(
    const int* __restrict__ src, const int* __restrict__ dst,
    const float* __restrict__ a_s, const float* __restrict__ a_d,
    const float* __restrict__ emax, float* __restrict__ denom, int ne)
{
    int e = blockIdx.x * 256 + threadIdx.x;
    if (e >= ne) return;
    int s = src[e], t = dst[e];
    atomicAdd(&denom[t], expf(lrelu(a_s[s] + a_d[t]) - emax[t]));
}

// 4 edge-slots of 64 threads each; EPB1 edges per block
#define EPB1 32
__global__ __launch_bounds__(256) void edge_aggr1(
    const int* __restrict__ src, const int* __restrict__ dst,
    const float* __restrict__ a_s, const float* __restrict__ a_d,
    const float* __restrict__ emax, const float* __restrict__ denom,
    const float* __restrict__ h2, float* __restrict__ dout, int ne)
{
    int tid = threadIdx.x;
    int slot = tid >> 6, c = tid & 63;
    int e0 = blockIdx.x * EPB1 + slot;
    #pragma unroll
    for (int i = 0; i < EPB1; i += 4) {
        int e = e0 + i;
        if (e >= ne) continue;         // wave-uniform
        int s = src[e], t = dst[e];
        float v = lrelu(a_s[s] + a_d[t]);
        float alpha = expf(v - emax[t]) / denom[t];
        atomicAdd(&dout[(long long)t * 64 + c], alpha * h2[(long long)s * 64 + c]);
    }
}

// ---------------------------------------------------------------------------
extern "C" void kernel_launch(void* const* d_in, const int* in_sizes, int n_in,
                              void* d_out, int out_size, void* d_ws, size_t ws_size,
                              hipStream_t stream)
{
    const float* x    = (const float*)d_in[0];
    const int*   ei   = (const int*)d_in[1];
    const float* W1   = (const float*)d_in[2];
    const float* as1  = (const float*)d_in[3];
    const float* ad1  = (const float*)d_in[4];
    const float* b1   = (const float*)d_in[5];
    const float* W2   = (const float*)d_in[6];
    const float* as2  = (const float*)d_in[7];
    const float* ad2  = (const float*)d_in[8];
    const float* b2   = (const float*)d_in[9];
    float* dout = (float*)d_out;

    const int n  = in_sizes[0] / H_IN;        // 50000
    const int ne = in_sizes[1] / 2;           // 800000
    const int* src = ei;
    const int* dst = ei + ne;

    float* ws = (float*)d_ws;
    float* h1     = ws;                         // n*256
    float* out1   = h1     + (size_t)n * 256;   // n*256
    float* a_s1   = out1   + (size_t)n * 256;   // n*4
    float* a_d1   = a_s1   + (size_t)n * 4;
    float* emax1  = a_d1   + (size_t)n * 4;
    float* denom1 = emax1  + (size_t)n * 4;
    float* h2     = denom1 + (size_t)n * 4;     // n*64
    float* a_s2   = h2     + (size_t)n * 64;    // n
    float* a_d2   = a_s2   + (size_t)n;
    float* emax2  = a_d2   + (size_t)n;
    float* denom2 = emax2  + (size_t)n;

    // init (bias pre-load + -inf/-zero segments)
    {
        long long tot = (long long)n * 256;
        int blocks = (int)((tot + 255) / 256);
        init_kernel<<<blocks, 256, 0, stream>>>(out1, b1, dout, b2,
                                                emax1, denom1, emax2, denom2, n);
    }

    // ---- layer 1 ----
    gemm1_att<<<(n + G1_ROWS - 1) / G1_ROWS, 256, 0, stream>>>(
        x, W1, as1, ad1, h1, a_s1, a_d1, n);
    {
        int eb = (ne + 255) / 256;
        edge_max4<<<eb, 256, 0, stream>>>(src, dst, (const float4*)a_s1,
                                          (const float4*)a_d1, emax1, ne);
        edge_denom4<<<eb, 256, 0, stream>>>(src, dst, (const float4*)a_s1,
                                            (const float4*)a_d1, (const float4*)emax1,
                                            denom1, ne);
    }
    edge_aggr4<<<(ne + EPB4 - 1) / EPB4, 256, 0, stream>>>(
        src, dst, a_s1, a_d1, emax1, denom1, h1, out1, ne);

    // ---- layer 2 ----
    gemm2_att<<<(n + G2_ROWS - 1) / G2_ROWS, 256, 0, stream>>>(
        out1, W2, as2, ad2, h2, a_s2, a_d2, n);
    {
        int eb = (ne + 255) / 256;
        edge_max1<<<eb, 256, 0, stream>>>(src, dst, a_s2, a_d2, emax2, ne);
        edge_denom1<<<eb, 256, 0, stream>>>(src, dst, a_s2, a_d2, emax2, denom2, ne);
    }
    edge_aggr1<<<(ne + EPB1 - 1) / EPB1, 256, 0, stream>>>(
        src, dst, a_s2, a_d2, emax2, denom2, h2, dout, ne);
}

// Round 3
// 620.365 us; speedup vs baseline: 2.4672x; 2.4672x over previous
//
#include <hip/hip_runtime.h>

#define NEG_SLOPE 0.2f
#define H_IN 64
#define HEADS1 4

__device__ __forceinline__ float lrelu(float v) { return v > 0.f ? v : NEG_SLOPE * v; }

// ---------------------------------------------------------------------------
// CSR build: zero -> hist -> block_sum -> scan_bsum -> scan_rowptr -> scatter
// (n assumed <= 256*256; n=50000 -> NB=196)
// ---------------------------------------------------------------------------
__global__ __launch_bounds__(256) void zero_int2(int* __restrict__ a,
                                                 int* __restrict__ b, int n)
{
    int i = blockIdx.x * 256 + threadIdx.x;
    if (i < n) { a[i] = 0; b[i] = 0; }
}

__global__ __launch_bounds__(256) void hist_kernel(const int* __restrict__ dst,
                                                   int* __restrict__ deg, int ne)
{
    int e = blockIdx.x * 256 + threadIdx.x;
    if (e < ne) atomicAdd(&deg[dst[e]], 1);
}

__global__ __launch_bounds__(256) void block_sum(const int* __restrict__ deg,
                                                 int* __restrict__ bsum, int n)
{
    __shared__ int part[4];
    int i = blockIdx.x * 256 + threadIdx.x;
    int v = (i < n) ? deg[i] : 0;
    #pragma unroll
    for (int off = 32; off; off >>= 1) v += __shfl_down(v, off);
    int lane = threadIdx.x & 63, wv = threadIdx.x >> 6;
    if (lane == 0) part[wv] = v;
    __syncthreads();
    if (threadIdx.x == 0)
        bsum[blockIdx.x] = part[0] + part[1] + part[2] + part[3];
}

__global__ __launch_bounds__(256) void scan_bsum(const int* __restrict__ bsum,
                                                 int* __restrict__ bpre, int nb)
{
    __shared__ int sm[256];
    int t = threadIdx.x;
    int v = (t < nb) ? bsum[t] : 0;
    sm[t] = v; __syncthreads();
    for (int off = 1; off < 256; off <<= 1) {
        int y = (t >= off) ? sm[t - off] : 0;
        __syncthreads();
        if (t >= off) sm[t] += y;
        __syncthreads();
    }
    if (t < nb) bpre[t] = sm[t] - v;   // exclusive
}

__global__ __launch_bounds__(256) void scan_rowptr(const int* __restrict__ deg,
                                                   const int* __restrict__ bpre,
                                                   int* __restrict__ rowptr, int n)
{
    __shared__ int sm[256];
    int t = threadIdx.x;
    int i = blockIdx.x * 256 + t;
    int v = (i < n) ? deg[i] : 0;
    sm[t] = v; __syncthreads();
    for (int off = 1; off < 256; off <<= 1) {
        int y = (t >= off) ? sm[t - off] : 0;
        __syncthreads();
        if (t >= off) sm[t] += y;
        __syncthreads();
    }
    if (i < n) rowptr[i] = sm[t] - v + bpre[blockIdx.x];
}

__global__ __launch_bounds__(256) void scatter_kernel(
    const int* __restrict__ src, const int* __restrict__ dst,
    const int* __restrict__ rowptr, int* __restrict__ cursor,
    int* __restrict__ csr_src, int ne)
{
    int e = blockIdx.x * 256 + threadIdx.x;
    if (e >= ne) return;
    int t = dst[e];
    int pos = atomicAdd(&cursor[t], 1);
    csr_src[rowptr[t] + pos] = src[e];
}

// ---------------------------------------------------------------------------
// layer-1 GEMM + attention logits: h1[N,256] = x[N,64] @ W1[64,256]
// ---------------------------------------------------------------------------
#define G1_ROWS 16
__global__ __launch_bounds__(256) void gemm1_att(
    const float* __restrict__ x, const float* __restrict__ W1,
    const float* __restrict__ atts, const float* __restrict__ attd,
    float* __restrict__ h1, float* __restrict__ a_s, float* __restrict__ a_d, int n)
{
    __shared__ float w_s[64 * 256];      // 64 KB
    __shared__ float x_s[G1_ROWS * 64];  // 4 KB
    int tid = threadIdx.x;
    for (int i = tid; i < 64 * 256; i += 256) w_s[i] = W1[i];
    int row0 = blockIdx.x * G1_ROWS;
    for (int i = tid; i < G1_ROWS * 64; i += 256) {
        int r = i >> 6, k = i & 63;
        int row = row0 + r;
        x_s[i] = (row < n) ? x[(long long)row * 64 + k] : 0.f;
    }
    __syncthreads();
    float as_w = atts[tid];   // att_src1[h][c], tid = h*64+c
    float ad_w = attd[tid];
    int head = tid >> 6;
    int lane = tid & 63;
    for (int r = 0; r < G1_ROWS; ++r) {
        int row = row0 + r;
        if (row >= n) break;           // uniform across block
        float acc = 0.f;
        #pragma unroll
        for (int k = 0; k < 64; ++k)
            acc = fmaf(x_s[r * 64 + k], w_s[k * 256 + tid], acc);
        h1[(long long)row * 256 + tid] = acc;
        float s = acc * as_w, d = acc * ad_w;
        #pragma unroll
        for (int off = 32; off > 0; off >>= 1) {
            s += __shfl_down(s, off);
            d += __shfl_down(d, off);
        }
        if (lane == 0) { a_s[row * 4 + head] = s; a_d[row * 4 + head] = d; }
    }
}

// ---------------------------------------------------------------------------
// layer-2 GEMM (input = relu(out1)) + attention logits (1 head)
// ---------------------------------------------------------------------------
#define G2_ROWS 16
__global__ __launch_bounds__(256) void gemm2_att(
    const float* __restrict__ out1, const float* __restrict__ W2,
    const float* __restrict__ atts, const float* __restrict__ attd,
    float* __restrict__ h2, float* __restrict__ a_s, float* __restrict__ a_d, int n)
{
    __shared__ float w_s[256 * 64];       // 64 KB
    __shared__ float x_s[G2_ROWS * 256];  // 16 KB
    int tid = threadIdx.x;
    for (int i = tid; i < 256 * 64; i += 256) w_s[i] = W2[i];
    int row0 = blockIdx.x * G2_ROWS;
    for (int i = tid; i < G2_ROWS * 256; i += 256) {
        int r = i >> 8, k = i & 255;
        int row = row0 + r;
        float v = (row < n) ? out1[(long long)row * 256 + k] : 0.f;
        x_s[i] = v > 0.f ? v : 0.f;      // fused ReLU
    }
    __syncthreads();
    int col = tid & 63;
    int rg  = tid >> 6;                  // 4 row-groups, one wave each
    float as_w = atts[col], ad_w = attd[col];
    for (int r = rg; r < G2_ROWS; r += 4) {
        int row = row0 + r;
        if (row >= n) continue;          // wave-uniform
        float acc = 0.f;
        #pragma unroll
        for (int k = 0; k < 256; ++k)
            acc = fmaf(x_s[r * 256 + k], w_s[k * 64 + col], acc);
        h2[(long long)row * 64 + col] = acc;
        float s = acc * as_w, d = acc * ad_w;
        #pragma unroll
        for (int off = 32; off > 0; off >>= 1) {
            s += __shfl_down(s, off);
            d += __shfl_down(d, off);
        }
        if (col == 0) { a_s[row] = s; a_d[row] = d; }
    }
}

// ---------------------------------------------------------------------------
// fused layer-1 softmax+aggregate: one block per dst node, wave == head.
// out1[t,:] = b1 + sum_e alpha_e * h1[src_e,:]
// ---------------------------------------------------------------------------
__global__ __launch_bounds__(256) void aggr1_csr(
    const int* __restrict__ rowptr, const int* __restrict__ deg,
    const int* __restrict__ csr_src,
    const float* __restrict__ a_s, const float* __restrict__ a_d,
    const float* __restrict__ h1, const float* __restrict__ b1,
    float* __restrict__ out1, int n)
{
    __shared__ float al[4][64];
    __shared__ int   ss[64];
    int t = blockIdx.x;
    int tid = threadIdx.x, h = tid >> 6, lane = tid & 63;
    int row0 = rowptr[t], d = deg[t];
    float adt = a_d[t * 4 + h];

    float m = -INFINITY;
    for (int i = lane; i < d; i += 64)
        m = fmaxf(m, lrelu(a_s[csr_src[row0 + i] * 4 + h] + adt));
    #pragma unroll
    for (int off = 32; off; off >>= 1) m = fmaxf(m, __shfl_xor(m, off));

    float dsum = 0.f;
    for (int i = lane; i < d; i += 64)
        dsum += __expf(lrelu(a_s[csr_src[row0 + i] * 4 + h] + adt) - m);
    #pragma unroll
    for (int off = 32; off; off >>= 1) dsum += __shfl_xor(dsum, off);
    float inv = (d > 0) ? 1.f / dsum : 0.f;

    float acc = 0.f;
    for (int c0 = 0; c0 < d; c0 += 64) {
        int i = c0 + lane;
        int s_l = 0; float alpha = 0.f;
        if (i < d) {
            s_l = csr_src[row0 + i];
            alpha = __expf(lrelu(a_s[s_l * 4 + h] + adt) - m) * inv;
        }
        al[h][lane] = alpha;
        if (h == 0) ss[lane] = s_l;
        __syncthreads();
        int cl = min(64, d - c0);
        for (int j = 0; j < cl; ++j)
            acc += al[h][j] * h1[(long long)ss[j] * 256 + tid];
        __syncthreads();
    }
    out1[(long long)t * 256 + tid] = acc + b1[tid];
}

// ---------------------------------------------------------------------------
// fused layer-2 softmax+aggregate: one wave per dst node (4 nodes/block)
// ---------------------------------------------------------------------------
__global__ __launch_bounds__(256) void aggr2_csr(
    const int* __restrict__ rowptr, const int* __restrict__ deg,
    const int* __restrict__ csr_src,
    const float* __restrict__ a_s, const float* __restrict__ a_d,
    const float* __restrict__ h2, const float* __restrict__ b2,
    float* __restrict__ dout, int n)
{
    int wv = threadIdx.x >> 6, lane = threadIdx.x & 63;
    int t = blockIdx.x * 4 + wv;
    if (t >= n) return;
    int row0 = rowptr[t], d = deg[t];
    float adt = a_d[t];

    float m = -INFINITY;
    for (int i = lane; i < d; i += 64)
        m = fmaxf(m, lrelu(a_s[csr_src[row0 + i]] + adt));
    #pragma unroll
    for (int off = 32; off; off >>= 1) m = fmaxf(m, __shfl_xor(m, off));

    float dsum = 0.f;
    for (int i = lane; i < d; i += 64)
        dsum += __expf(lrelu(a_s[csr_src[row0 + i]] + adt) - m);
    #pragma unroll
    for (int off = 32; off; off >>= 1) dsum += __shfl_xor(dsum, off);
    float inv = (d > 0) ? 1.f / dsum : 0.f;

    float acc = 0.f;
    for (int c0 = 0; c0 < d; c0 += 64) {
        int i = c0 + lane;
        int s_l = 0; float alpha = 0.f;
        if (i < d) {
            s_l = csr_src[row0 + i];
            alpha = __expf(lrelu(a_s[s_l] + adt) - m) * inv;
        }
        int cl = min(64, d - c0);
        for (int j = 0; j < cl; ++j) {
            float a  = __shfl(alpha, j);
            int   si = __shfl(s_l, j);
            acc += a * h2[(long long)si * 64 + lane];
        }
    }
    dout[(long long)t * 64 + lane] = acc + b2[lane];
}

// ---------------------------------------------------------------------------
extern "C" void kernel_launch(void* const* d_in, const int* in_sizes, int n_in,
                              void* d_out, int out_size, void* d_ws, size_t ws_size,
                              hipStream_t stream)
{
    const float* x    = (const float*)d_in[0];
    const int*   ei   = (const int*)d_in[1];
    const float* W1   = (const float*)d_in[2];
    const float* as1  = (const float*)d_in[3];
    const float* ad1  = (const float*)d_in[4];
    const float* b1   = (const float*)d_in[5];
    const float* W2   = (const float*)d_in[6];
    const float* as2  = (const float*)d_in[7];
    const float* ad2  = (const float*)d_in[8];
    const float* b2   = (const float*)d_in[9];
    float* dout = (float*)d_out;

    const int n  = in_sizes[0] / H_IN;        // 50000
    const int ne = in_sizes[1] / 2;           // 800000
    const int* src = ei;
    const int* dst = ei + ne;
    const int NB = (n + 255) / 256;           // 196

    float* ws = (float*)d_ws;
    float* h1     = ws;                           // n*256 (later reused for h2/a_s2/a_d2)
    float* out1   = h1   + (size_t)n * 256;       // n*256
    float* a_s1   = out1 + (size_t)n * 256;       // n*4
    float* a_d1   = a_s1 + (size_t)n * 4;         // n*4
    int*   deg    = (int*)(a_d1 + (size_t)n * 4); // n
    int*   rowptr = deg + n;                      // n
    int*   csr    = rowptr + n;                   // ne
    int*   bsum   = csr + ne;                     // NB
    int*   bpre   = bsum + NB;                    // NB
    int*   cursor = (int*)h1;                     // n (dead before h1 is written)
    // layer-2 buffers overlay h1 (h1 dead after aggr1_csr)
    float* h2   = h1;                             // n*64
    float* a_s2 = h1 + (size_t)n * 64;            // n
    float* a_d2 = a_s2 + n;                       // n

    // ---- CSR build (shared by both layers) ----
    zero_int2<<<NB, 256, 0, stream>>>(deg, cursor, n);
    hist_kernel<<<(ne + 255) / 256, 256, 0, stream>>>(dst, deg, ne);
    block_sum<<<NB, 256, 0, stream>>>(deg, bsum, n);
    scan_bsum<<<1, 256, 0, stream>>>(bsum, bpre, NB);
    scan_rowptr<<<NB, 256, 0, stream>>>(deg, bpre, rowptr, n);
    scatter_kernel<<<(ne + 255) / 256, 256, 0, stream>>>(src, dst, rowptr, cursor, csr, ne);

    // ---- layer 1 ----
    gemm1_att<<<(n + G1_ROWS - 1) / G1_ROWS, 256, 0, stream>>>(
        x, W1, as1, ad1, h1, a_s1, a_d1, n);
    aggr1_csr<<<n, 256, 0, stream>>>(rowptr, deg, csr, a_s1, a_d1, h1, b1, out1, n);

    // ---- layer 2 ----
    gemm2_att<<<(n + G2_ROWS - 1) / G2_ROWS, 256, 0, stream>>>(
        out1, W2, as2, ad2, h2, a_s2, a_d2, n);
    aggr2_csr<<<(n + 3) / 4, 256, 0, stream>>>(rowptr, deg, csr, a_s2, a_d2, h2, b2, dout, n);
}

// Round 5
// 543.936 us; speedup vs baseline: 2.8139x; 1.1405x over previous
//
#include <hip/hip_runtime.h>

#define NEG_SLOPE 0.2f
#define H_IN 64

__device__ __forceinline__ float lrelu(float v) { return v > 0.f ? v : NEG_SLOPE * v; }

// ---------------------------------------------------------------------------
// CSR build: zero -> hist -> block_sum -> scan_bsum -> scan_rowptr -> scatter
// ---------------------------------------------------------------------------
__global__ __launch_bounds__(256) void zero_int2(int* __restrict__ a,
                                                 int* __restrict__ b, int n)
{
    int i = blockIdx.x * 256 + threadIdx.x;
    if (i < n) { a[i] = 0; b[i] = 0; }
}

__global__ __launch_bounds__(256) void hist_kernel(const int* __restrict__ dst,
                                                   int* __restrict__ deg, int ne)
{
    int e = blockIdx.x * 256 + threadIdx.x;
    if (e < ne) atomicAdd(&deg[dst[e]], 1);
}

__global__ __launch_bounds__(256) void block_sum(const int* __restrict__ deg,
                                                 int* __restrict__ bsum, int n)
{
    __shared__ int part[4];
    int i = blockIdx.x * 256 + threadIdx.x;
    int v = (i < n) ? deg[i] : 0;
    #pragma unroll
    for (int off = 32; off; off >>= 1) v += __shfl_down(v, off);
    int lane = threadIdx.x & 63, wv = threadIdx.x >> 6;
    if (lane == 0) part[wv] = v;
    __syncthreads();
    if (threadIdx.x == 0)
        bsum[blockIdx.x] = part[0] + part[1] + part[2] + part[3];
}

__global__ __launch_bounds__(256) void scan_bsum(const int* __restrict__ bsum,
                                                 int* __restrict__ bpre, int nb)
{
    __shared__ int sm[256];
    int t = threadIdx.x;
    int v = (t < nb) ? bsum[t] : 0;
    sm[t] = v; __syncthreads();
    for (int off = 1; off < 256; off <<= 1) {
        int y = (t >= off) ? sm[t - off] : 0;
        __syncthreads();
        if (t >= off) sm[t] += y;
        __syncthreads();
    }
    if (t < nb) bpre[t] = sm[t] - v;   // exclusive
}

__global__ __launch_bounds__(256) void scan_rowptr(const int* __restrict__ deg,
                                                   const int* __restrict__ bpre,
                                                   int* __restrict__ rowptr, int n)
{
    __shared__ int sm[256];
    int t = threadIdx.x;
    int i = blockIdx.x * 256 + t;
    int v = (i < n) ? deg[i] : 0;
    sm[t] = v; __syncthreads();
    for (int off = 1; off < 256; off <<= 1) {
        int y = (t >= off) ? sm[t - off] : 0;
        __syncthreads();
        if (t >= off) sm[t] += y;
        __syncthreads();
    }
    if (i < n) rowptr[i] = sm[t] - v + bpre[blockIdx.x];
}

__global__ __launch_bounds__(256) void scatter_kernel(
    const int* __restrict__ src, const int* __restrict__ dst,
    const int* __restrict__ rowptr, int* __restrict__ cursor,
    int* __restrict__ csr_src, int ne)
{
    int e = blockIdx.x * 256 + threadIdx.x;
    if (e >= ne) return;
    int t = dst[e];
    int pos = atomicAdd(&cursor[t], 1);
    csr_src[rowptr[t] + pos] = src[e];
}

// ---------------------------------------------------------------------------
// micro: wa1s/wa1d[k*4+h] = sum_c W1[k,h*64+c]*att1[h,c];  wa2s/wa2d[k] likewise
// ---------------------------------------------------------------------------
__global__ __launch_bounds__(256) void micro_wa(
    const float* __restrict__ W1, const float* __restrict__ as1, const float* __restrict__ ad1,
    const float* __restrict__ W2, const float* __restrict__ as2, const float* __restrict__ ad2,
    float* __restrict__ wa1s, float* __restrict__ wa1d,
    float* __restrict__ wa2s, float* __restrict__ wa2d)
{
    int tid = threadIdx.x;
    int k = tid >> 2, h = tid & 3;
    float s = 0.f, d = 0.f;
    #pragma unroll 8
    for (int c = 0; c < 64; ++c) {
        float w = W1[k * 256 + h * 64 + c];
        s = fmaf(w, as1[h * 64 + c], s);
        d = fmaf(w, ad1[h * 64 + c], d);
    }
    wa1s[k * 4 + h] = s; wa1d[k * 4 + h] = d;
    float s2 = 0.f, d2 = 0.f;
    #pragma unroll 8
    for (int c = 0; c < 64; ++c) {
        float w = W2[tid * 64 + c];
        s2 = fmaf(w, as2[c], s2);
        d2 = fmaf(w, ad2[c], d2);
    }
    wa2s[tid] = s2; wa2d[tid] = d2;
}

// ---------------------------------------------------------------------------
// axw1: a_s1[row,h] = sum_k x[row,k]*wa1s[k,h]  (and a_d1)
// ---------------------------------------------------------------------------
__global__ __launch_bounds__(256) void axw1_kernel(
    const float* __restrict__ x,
    const float* __restrict__ wa1s, const float* __restrict__ wa1d,
    float* __restrict__ a_s, float* __restrict__ a_d, int n)
{
    __shared__ float ws[256], wd[256];
    int tid = threadIdx.x;
    ws[tid] = wa1s[tid]; wd[tid] = wa1d[tid];
    __syncthreads();
    int row = blockIdx.x * 256 + tid;
    if (row >= n) return;
    const float4* xv = (const float4*)(x + (size_t)row * 64);
    float aS[4] = {0, 0, 0, 0}, aD[4] = {0, 0, 0, 0};
    #pragma unroll
    for (int k4 = 0; k4 < 16; ++k4) {
        float4 q = xv[k4];
        float xe[4] = {q.x, q.y, q.z, q.w};
        #pragma unroll
        for (int e = 0; e < 4; ++e) {
            int k = k4 * 4 + e;
            #pragma unroll
            for (int h = 0; h < 4; ++h) {
                aS[h] = fmaf(xe[e], ws[k * 4 + h], aS[h]);
                aD[h] = fmaf(xe[e], wd[k * 4 + h], aD[h]);
            }
        }
    }
    #pragma unroll
    for (int h = 0; h < 4; ++h) {
        a_s[row * 4 + h] = aS[h];
        a_d[row * 4 + h] = aD[h];
    }
}

// ---------------------------------------------------------------------------
// gemm1: h1[N,256] = x[N,64] @ W1[64,256]; 16 rows/block, 4-row register subtiles,
// x via wave-uniform scalar loads, W in LDS.
// ---------------------------------------------------------------------------
__global__ __launch_bounds__(256) void gemm1_kernel(
    const float* __restrict__ x, const float* __restrict__ W1,
    float* __restrict__ h1, int n)
{
    __shared__ float w_s[64 * 256];
    int tid = threadIdx.x;
    {
        const float4* Wv = (const float4*)W1;
        float4* wv = (float4*)w_s;
        for (int i = tid; i < 4096; i += 256) wv[i] = Wv[i];
    }
    __syncthreads();
    int row0 = blockIdx.x * 16;             // n divisible by 16
    for (int sub = 0; sub < 4; ++sub) {
        const float* x0 = x + (size_t)(row0 + sub * 4) * 64;
        const float* x1 = x0 + 64;
        const float* x2 = x0 + 128;
        const float* x3 = x0 + 192;
        float a0 = 0.f, a1 = 0.f, a2 = 0.f, a3 = 0.f;
        #pragma unroll
        for (int k = 0; k < 64; ++k) {
            float w = w_s[k * 256 + tid];
            a0 = fmaf(x0[k], w, a0);
            a1 = fmaf(x1[k], w, a1);
            a2 = fmaf(x2[k], w, a2);
            a3 = fmaf(x3[k], w, a3);
        }
        size_t base = (size_t)(row0 + sub * 4) * 256 + tid;
        h1[base]       = a0;
        h1[base + 256] = a1;
        h1[base + 512] = a2;
        h1[base + 768] = a3;
    }
}

// ---------------------------------------------------------------------------
// gemm2: h2[N,64] = out1r[N,256] @ W2[256,64]; 64 rows/block (16/wave),
// 4-row register subtiles, x via scalar loads, W2 in LDS.
// ---------------------------------------------------------------------------
__global__ __launch_bounds__(256) void gemm2_kernel(
    const float* __restrict__ xr, const float* __restrict__ W2,
    float* __restrict__ h2, int n)
{
    __shared__ float w_s[256 * 64];
    int tid = threadIdx.x;
    {
        const float4* Wv = (const float4*)W2;
        float4* wv = (float4*)w_s;
        for (int i = tid; i < 4096; i += 256) wv[i] = Wv[i];
    }
    __syncthreads();
    int col = tid & 63, wv_ = tid >> 6;
    int row0 = blockIdx.x * 64 + wv_ * 16;
    for (int sub = 0; sub < 4; ++sub) {
        int r0 = row0 + sub * 4;
        const float* x0 = xr + (size_t)r0 * 256;
        const float* x1 = x0 + 256;
        const float* x2 = x0 + 512;
        const float* x3 = x0 + 768;
        float a0 = 0.f, a1 = 0.f, a2 = 0.f, a3 = 0.f;
        #pragma unroll 32
        for (int k = 0; k < 256; ++k) {
            float w = w_s[k * 64 + col];
            a0 = fmaf(x0[k], w, a0);
            a1 = fmaf(x1[k], w, a1);
            a2 = fmaf(x2[k], w, a2);
            a3 = fmaf(x3[k], w, a3);
        }
        if (r0 + 3 < n) {
            size_t b = (size_t)r0 * 64 + col;
            h2[b]       = a0;
            h2[b + 64]  = a1;
            h2[b + 128] = a2;
            h2[b + 192] = a3;
        } else {
            float av[4] = {a0, a1, a2, a3};
            for (int r = 0; r < 4; ++r)
                if (r0 + r < n) h2[(size_t)(r0 + r) * 64 + col] = av[r];
        }
    }
}

// ---------------------------------------------------------------------------
// fused layer-1 softmax+aggregate+bias+relu + layer-2 logits.
// one block per dst node, wave == head.
// ---------------------------------------------------------------------------
__global__ __launch_bounds__(256) void aggr1_csr(
    const int* __restrict__ rowptr, const int* __restrict__ deg,
    const int* __restrict__ csr_src,
    const float* __restrict__ a_s, const float* __restrict__ a_d,
    const float* __restrict__ h1, const float* __restrict__ b1,
    const float* __restrict__ wa2s, const float* __restrict__ wa2d,
    float* __restrict__ out1r, float* __restrict__ a_s2, float* __restrict__ a_d2,
    int n)
{
    __shared__ float al[4][64];
    __shared__ int   ss[64];
    __shared__ float ev[4][128];
    __shared__ float p1[4], p2[4];
    int t = blockIdx.x;
    int tid = threadIdx.x, h = tid >> 6, lane = tid & 63;
    int row0 = rowptr[t], d = deg[t];
    float adt = a_d[t * 4 + h];
    float w2s = wa2s[tid], w2d = wa2d[tid];
    bool small = (d <= 128);

    float m = -INFINITY;
    if (small) {
        for (int i = lane; i < d; i += 64) {
            float v = lrelu(a_s[csr_src[row0 + i] * 4 + h] + adt);
            ev[h][i] = v;
            m = fmaxf(m, v);
        }
    } else {
        for (int i = lane; i < d; i += 64)
            m = fmaxf(m, lrelu(a_s[csr_src[row0 + i] * 4 + h] + adt));
    }
    #pragma unroll
    for (int off = 32; off; off >>= 1) m = fmaxf(m, __shfl_xor(m, off));

    float dsum = 0.f;
    if (small) {
        for (int i = lane; i < d; i += 64) dsum += __expf(ev[h][i] - m);
    } else {
        for (int i = lane; i < d; i += 64)
            dsum += __expf(lrelu(a_s[csr_src[row0 + i] * 4 + h] + adt) - m);
    }
    #pragma unroll
    for (int off = 32; off; off >>= 1) dsum += __shfl_xor(dsum, off);
    float inv = (d > 0) ? 1.f / dsum : 0.f;

    float acc = 0.f;
    for (int c0 = 0; c0 < d; c0 += 64) {
        int i = c0 + lane;
        float alpha = 0.f;
        if (i < d) {
            float v = small ? ev[h][i] : lrelu(a_s[csr_src[row0 + i] * 4 + h] + adt);
            alpha = __expf(v - m) * inv;
        }
        al[h][lane] = alpha;
        if (h == 0) ss[lane] = (i < d) ? csr_src[row0 + i] * 256 : 0;
        __syncthreads();
        int cl = min(64, d - c0);
        const float* hp = h1 + tid;
        int j = 0;
        for (; j + 4 <= cl; j += 4) {
            int o0 = ss[j], o1 = ss[j + 1], o2 = ss[j + 2], o3 = ss[j + 3];
            float b0 = al[h][j], c1 = al[h][j + 1], c2 = al[h][j + 2], c3 = al[h][j + 3];
            float v0 = hp[o0], v1 = hp[o1], v2 = hp[o2], v3 = hp[o3];
            acc = fmaf(b0, v0, acc);
            acc = fmaf(c1, v1, acc);
            acc = fmaf(c2, v2, acc);
            acc = fmaf(c3, v3, acc);
        }
        for (; j < cl; ++j) acc = fmaf(al[h][j], hp[ss[j]], acc);
        __syncthreads();
    }

    float r = fmaxf(acc + b1[tid], 0.f);
    out1r[(size_t)t * 256 + tid] = r;
    float s2 = r * w2s, d2v = r * w2d;
    #pragma unroll
    for (int off = 32; off; off >>= 1) {
        s2  += __shfl_down(s2, off);
        d2v += __shfl_down(d2v, off);
    }
    if (lane == 0) { p1[h] = s2; p2[h] = d2v; }
    __syncthreads();
    if (tid == 0) {
        a_s2[t] = p1[0] + p1[1] + p1[2] + p1[3];
        a_d2[t] = p2[0] + p2[1] + p2[2] + p2[3];
    }
}

// ---------------------------------------------------------------------------
// fused layer-2 softmax+aggregate: one wave per dst node, wave-private LDS,
// no barriers.
// ---------------------------------------------------------------------------
__global__ __launch_bounds__(256) void aggr2_csr(
    const int* __restrict__ rowptr, const int* __restrict__ deg,
    const int* __restrict__ csr_src,
    const float* __restrict__ a_s, const float* __restrict__ a_d,
    const float* __restrict__ h2, const float* __restrict__ b2,
    float* __restrict__ dout, int n)
{
    __shared__ float ev2[4][128];
    __shared__ float al2[4][64];
    __shared__ int   ss2[4][64];
    int wv = threadIdx.x >> 6, lane = threadIdx.x & 63;
    int t = blockIdx.x * 4 + wv;
    if (t >= n) return;
    int row0 = rowptr[t], d = deg[t];
    float adt = a_d[t];
    bool small = (d <= 128);

    float m = -INFINITY;
    if (small) {
        for (int i = lane; i < d; i += 64) {
            float v = lrelu(a_s[csr_src[row0 + i]] + adt);
            ev2[wv][i] = v;
            m = fmaxf(m, v);
        }
    } else {
        for (int i = lane; i < d; i += 64)
            m = fmaxf(m, lrelu(a_s[csr_src[row0 + i]] + adt));
    }
    #pragma unroll
    for (int off = 32; off; off >>= 1) m = fmaxf(m, __shfl_xor(m, off));

    float dsum = 0.f;
    if (small) {
        for (int i = lane; i < d; i += 64) dsum += __expf(ev2[wv][i] - m);
    } else {
        for (int i = lane; i < d; i += 64)
            dsum += __expf(lrelu(a_s[csr_src[row0 + i]] + adt) - m);
    }
    #pragma unroll
    for (int off = 32; off; off >>= 1) dsum += __shfl_xor(dsum, off);
    float inv = (d > 0) ? 1.f / dsum : 0.f;

    float acc = 0.f;
    for (int c0 = 0; c0 < d; c0 += 64) {
        int i = c0 + lane;
        float alpha = 0.f; int so = 0;
        if (i < d) {
            int s = csr_src[row0 + i];
            so = s * 64;
            float v = small ? ev2[wv][i] : lrelu(a_s[s] + adt);
            alpha = __expf(v - m) * inv;
        }
        al2[wv][lane] = alpha;
        ss2[wv][lane] = so;
        int cl = min(64, d - c0);
        const float* hp = h2 + lane;
        int j = 0;
        for (; j + 4 <= cl; j += 4) {
            int o0 = ss2[wv][j], o1 = ss2[wv][j + 1], o2 = ss2[wv][j + 2], o3 = ss2[wv][j + 3];
            float b0 = al2[wv][j], c1 = al2[wv][j + 1], c2 = al2[wv][j + 2], c3 = al2[wv][j + 3];
            float v0 = hp[o0], v1 = hp[o1], v2 = hp[o2], v3 = hp[o3];
            acc = fmaf(b0, v0, acc);
            acc = fmaf(c1, v1, acc);
            acc = fmaf(c2, v2, acc);
            acc = fmaf(c3, v3, acc);
        }
        for (; j < cl; ++j) acc = fmaf(al2[wv][j], hp[ss2[wv][j]], acc);
    }
    dout[(size_t)t * 64 + lane] = acc + b2[lane];
}

// ---------------------------------------------------------------------------
extern "C" void kernel_launch(void* const* d_in, const int* in_sizes, int n_in,
                              void* d_out, int out_size, void* d_ws, size_t ws_size,
                              hipStream_t stream)
{
    const float* x    = (const float*)d_in[0];
    const int*   ei   = (const int*)d_in[1];
    const float* W1   = (const float*)d_in[2];
    const float* as1  = (const float*)d_in[3];
    const float* ad1  = (const float*)d_in[4];
    const float* b1   = (const float*)d_in[5];
    const float* W2   = (const float*)d_in[6];
    const float* as2  = (const float*)d_in[7];
    const float* ad2  = (const float*)d_in[8];
    const float* b2   = (const float*)d_in[9];
    float* dout = (float*)d_out;

    const int n  = in_sizes[0] / H_IN;        // 50000
    const int ne = in_sizes[1] / 2;           // 800000
    const int* src = ei;
    const int* dst = ei + ne;
    const int NB = (n + 255) / 256;           // 196

    float* ws = (float*)d_ws;
    float* h1     = ws;                             // n*256 (reused as h2)
    float* out1r  = h1     + (size_t)n * 256;       // n*256
    float* a_s1   = out1r  + (size_t)n * 256;       // n*4
    float* a_d1   = a_s1   + (size_t)n * 4;         // n*4
    float* a_s2   = a_d1   + (size_t)n * 4;         // n
    float* a_d2   = a_s2   + (size_t)n;             // n
    float* wa1s   = a_d2   + (size_t)n;             // 256
    float* wa1d   = wa1s + 256;                     // 256
    float* wa2s   = wa1d + 256;                     // 256
    float* wa2d   = wa2s + 256;                     // 256
    int*   deg    = (int*)(wa2d + 256);             // n
    int*   rowptr = deg + n;                        // n
    int*   csr    = rowptr + n;                     // ne
    int*   bsum   = csr + ne;                       // NB
    int*   bpre   = bsum + NB;                      // NB
    int*   cursor = (int*)h1;                       // n (dead before gemm1 writes h1)
    float* h2     = h1;                             // n*64 (h1 dead after aggr1)

    // ---- precompute W·att ----
    micro_wa<<<1, 256, 0, stream>>>(W1, as1, ad1, W2, as2, ad2, wa1s, wa1d, wa2s, wa2d);

    // ---- CSR build ----
    zero_int2<<<NB, 256, 0, stream>>>(deg, cursor, n);
    hist_kernel<<<(ne + 255) / 256, 256, 0, stream>>>(dst, deg, ne);
    block_sum<<<NB, 256, 0, stream>>>(deg, bsum, n);
    scan_bsum<<<1, 256, 0, stream>>>(bsum, bpre, NB);
    scan_rowptr<<<NB, 256, 0, stream>>>(deg, bpre, rowptr, n);
    scatter_kernel<<<(ne + 255) / 256, 256, 0, stream>>>(src, dst, rowptr, cursor, csr, ne);

    // ---- layer 1 ----
    axw1_kernel<<<NB, 256, 0, stream>>>(x, wa1s, wa1d, a_s1, a_d1, n);
    gemm1_kernel<<<n / 16, 256, 0, stream>>>(x, W1, h1, n);
    aggr1_csr<<<n, 256, 0, stream>>>(rowptr, deg, csr, a_s1, a_d1, h1, b1,
                                     wa2s, wa2d, out1r, a_s2, a_d2, n);

    // ---- layer 2 ----
    gemm2_kernel<<<(n + 63) / 64, 256, 0, stream>>>(out1r, W2, h2, n);
    aggr2_csr<<<(n + 3) / 4, 256, 0, stream>>>(rowptr, deg, csr, a_s2, a_d2, h2, b2, dout, n);
}

// Round 8
// 496.121 us; speedup vs baseline: 3.0851x; 1.0964x over previous
//
#include <hip/hip_runtime.h>
#include <hip/hip_fp16.h>

#define NEG_SLOPE 0.2f
#define H_IN 64

__device__ __forceinline__ float lrelu(float v) { return v > 0.f ? v : NEG_SLOPE * v; }

// ---------------------------------------------------------------------------
// CSR build: zero -> hist -> block_sum -> scan_bsum -> scan_rowptr -> scatter
// ---------------------------------------------------------------------------
__global__ __launch_bounds__(256) void zero_int2(int* __restrict__ a,
                                                 int* __restrict__ b, int n)
{
    int i = blockIdx.x * 256 + threadIdx.x;
    if (i < n) { a[i] = 0; b[i] = 0; }
}

__global__ __launch_bounds__(256) void hist_kernel(const int* __restrict__ dst,
                                                   int* __restrict__ deg, int ne)
{
    int e = blockIdx.x * 256 + threadIdx.x;
    if (e < ne) atomicAdd(&deg[dst[e]], 1);
}

__global__ __launch_bounds__(256) void block_sum(const int* __restrict__ deg,
                                                 int* __restrict__ bsum, int n)
{
    __shared__ int part[4];
    int i = blockIdx.x * 256 + threadIdx.x;
    int v = (i < n) ? deg[i] : 0;
    #pragma unroll
    for (int off = 32; off; off >>= 1) v += __shfl_down(v, off);
    int lane = threadIdx.x & 63, wv = threadIdx.x >> 6;
    if (lane == 0) part[wv] = v;
    __syncthreads();
    if (threadIdx.x == 0)
        bsum[blockIdx.x] = part[0] + part[1] + part[2] + part[3];
}

__global__ __launch_bounds__(256) void scan_bsum(const int* __restrict__ bsum,
                                                 int* __restrict__ bpre, int nb)
{
    __shared__ int sm[256];
    int t = threadIdx.x;
    int v = (t < nb) ? bsum[t] : 0;
    sm[t] = v; __syncthreads();
    for (int off = 1; off < 256; off <<= 1) {
        int y = (t >= off) ? sm[t - off] : 0;
        __syncthreads();
        if (t >= off) sm[t] += y;
        __syncthreads();
    }
    if (t < nb) bpre[t] = sm[t] - v;   // exclusive
}

__global__ __launch_bounds__(256) void scan_rowptr(const int* __restrict__ deg,
                                                   const int* __restrict__ bpre,
                                                   int* __restrict__ rowptr, int n)
{
    __shared__ int sm[256];
    int t = threadIdx.x;
    int i = blockIdx.x * 256 + t;
    int v = (i < n) ? deg[i] : 0;
    sm[t] = v; __syncthreads();
    for (int off = 1; off < 256; off <<= 1) {
        int y = (t >= off) ? sm[t - off] : 0;
        __syncthreads();
        if (t >= off) sm[t] += y;
        __syncthreads();
    }
    if (i < n) rowptr[i] = sm[t] - v + bpre[blockIdx.x];
}

__global__ __launch_bounds__(256) void scatter_kernel(
    const int* __restrict__ src, const int* __restrict__ dst,
    const int* __restrict__ rowptr, int* __restrict__ cursor,
    int* __restrict__ csr_src, int ne)
{
    int e = blockIdx.x * 256 + threadIdx.x;
    if (e >= ne) return;
    int t = dst[e];
    int pos = atomicAdd(&cursor[t], 1);
    csr_src[rowptr[t] + pos] = src[e];
}

// ---------------------------------------------------------------------------
// micro: wa1s/wa1d[k*4+h] = sum_c W1[k,h*64+c]*att1[h,c];  wa2s/wa2d[k] likewise
// ---------------------------------------------------------------------------
__global__ __launch_bounds__(256) void micro_wa(
    const float* __restrict__ W1, const float* __restrict__ as1, const float* __restrict__ ad1,
    const float* __restrict__ W2, const float* __restrict__ as2, const float* __restrict__ ad2,
    float* __restrict__ wa1s, float* __restrict__ wa1d,
    float* __restrict__ wa2s, float* __restrict__ wa2d)
{
    int tid = threadIdx.x;
    int k = tid >> 2, h = tid & 3;
    float s = 0.f, d = 0.f;
    #pragma unroll 8
    for (int c = 0; c < 64; ++c) {
        float w = W1[k * 256 + h * 64 + c];
        s = fmaf(w, as1[h * 64 + c], s);
        d = fmaf(w, ad1[h * 64 + c], d);
    }
    wa1s[k * 4 + h] = s; wa1d[k * 4 + h] = d;
    float s2 = 0.f, d2 = 0.f;
    #pragma unroll 8
    for (int c = 0; c < 64; ++c) {
        float w = W2[tid * 64 + c];
        s2 = fmaf(w, as2[c], s2);
        d2 = fmaf(w, ad2[c], d2);
    }
    wa2s[tid] = s2; wa2d[tid] = d2;
}

// ---------------------------------------------------------------------------
// axw1: a_s1[row,h] = sum_k x[row,k]*wa1s[k,h]  (and a_d1)
// ---------------------------------------------------------------------------
__global__ __launch_bounds__(256) void axw1_kernel(
    const float* __restrict__ x,
    const float* __restrict__ wa1s, const float* __restrict__ wa1d,
    float* __restrict__ a_s, float* __restrict__ a_d, int n)
{
    __shared__ float ws[256], wd[256];
    int tid = threadIdx.x;
    ws[tid] = wa1s[tid]; wd[tid] = wa1d[tid];
    __syncthreads();
    int row = blockIdx.x * 256 + tid;
    if (row >= n) return;
    const float4* xv = (const float4*)(x + (size_t)row * 64);
    float aS[4] = {0, 0, 0, 0}, aD[4] = {0, 0, 0, 0};
    #pragma unroll
    for (int k4 = 0; k4 < 16; ++k4) {
        float4 q = xv[k4];
        float xe[4] = {q.x, q.y, q.z, q.w};
        #pragma unroll
        for (int e = 0; e < 4; ++e) {
            int k = k4 * 4 + e;
            #pragma unroll
            for (int h = 0; h < 4; ++h) {
                aS[h] = fmaf(xe[e], ws[k * 4 + h], aS[h]);
                aD[h] = fmaf(xe[e], wd[k * 4 + h], aD[h]);
            }
        }
    }
    #pragma unroll
    for (int h = 0; h < 4; ++h) {
        a_s[row * 4 + h] = aS[h];
        a_d[row * 4 + h] = aD[h];
    }
}

// ---------------------------------------------------------------------------
// gemm1: h1[N,256] (fp16) = x[N,64] @ W1[64,256]; 16 rows/block,
// 4-row register subtiles, x via uniform float4 loads (row = 16 float4s).
// ---------------------------------------------------------------------------
__global__ __launch_bounds__(256) void gemm1_kernel(
    const float* __restrict__ x, const float* __restrict__ W1,
    __half* __restrict__ h1, int n)
{
    __shared__ float w_s[64 * 256];
    int tid = threadIdx.x;
    {
        const float4* Wv = (const float4*)W1;
        float4* wv = (float4*)w_s;
        for (int i = tid; i < 4096; i += 256) wv[i] = Wv[i];
    }
    __syncthreads();
    int row0 = blockIdx.x * 16;             // n divisible by 16
    for (int sub = 0; sub < 4; ++sub) {
        const float4* x0 = (const float4*)(x + (size_t)(row0 + sub * 4) * 64);
        const float4* x1 = x0 + 16;         // fp32 row = 64 floats = 16 float4
        const float4* x2 = x0 + 32;
        const float4* x3 = x0 + 48;
        float a0 = 0.f, a1 = 0.f, a2 = 0.f, a3 = 0.f;
        #pragma unroll
        for (int k4 = 0; k4 < 16; ++k4) {
            float4 q0 = x0[k4], q1 = x1[k4], q2 = x2[k4], q3 = x3[k4];
            const float* f0 = (const float*)&q0;
            const float* f1 = (const float*)&q1;
            const float* f2 = (const float*)&q2;
            const float* f3 = (const float*)&q3;
            #pragma unroll
            for (int e = 0; e < 4; ++e) {
                float w = w_s[(k4 * 4 + e) * 256 + tid];
                a0 = fmaf(f0[e], w, a0);
                a1 = fmaf(f1[e], w, a1);
                a2 = fmaf(f2[e], w, a2);
                a3 = fmaf(f3[e], w, a3);
            }
        }
        size_t base = (size_t)(row0 + sub * 4) * 256 + tid;
        h1[base]       = __float2half(a0);
        h1[base + 256] = __float2half(a1);
        h1[base + 512] = __float2half(a2);
        h1[base + 768] = __float2half(a3);
    }
}

// ---------------------------------------------------------------------------
// gemm2: h2[N,64] (fp16) = out1r[N,256] (fp16) @ W2[256,64]; 64 rows/block
// (16/wave). fp16 row = 256 halves = 512 B = 32 float4s  <-- stride fix.
// ---------------------------------------------------------------------------
__global__ __launch_bounds__(256) void gemm2_kernel(
    const __half* __restrict__ xr, const float* __restrict__ W2,
    __half* __restrict__ h2, int n)
{
    __shared__ float w_s[256 * 64];
    int tid = threadIdx.x;
    {
        const float4* Wv = (const float4*)W2;
        float4* wv = (float4*)w_s;
        for (int i = tid; i < 4096; i += 256) wv[i] = Wv[i];
    }
    __syncthreads();
    int col = tid & 63, wv_ = tid >> 6;
    int row0 = blockIdx.x * 64 + wv_ * 16;
    for (int sub = 0; sub < 4; ++sub) {
        int r0 = row0 + sub * 4;
        const float4* x0 = (const float4*)(xr + (size_t)r0 * 256);  // 16B = 8 halves
        const float4* x1 = x0 + 32;    // fp16 row = 256 halves = 32 float4
        const float4* x2 = x0 + 64;
        const float4* x3 = x0 + 96;
        float a0 = 0.f, a1 = 0.f, a2 = 0.f, a3 = 0.f;
        #pragma unroll 8
        for (int k8 = 0; k8 < 32; ++k8) {
            float4 q0 = x0[k8], q1 = x1[k8], q2 = x2[k8], q3 = x3[k8];
            const __half2* p0 = (const __half2*)&q0;
            const __half2* p1 = (const __half2*)&q1;
            const __half2* p2 = (const __half2*)&q2;
            const __half2* p3 = (const __half2*)&q3;
            #pragma unroll
            for (int e = 0; e < 4; ++e) {
                float2 g0 = __half22float2(p0[e]);
                float2 g1 = __half22float2(p1[e]);
                float2 g2 = __half22float2(p2[e]);
                float2 g3 = __half22float2(p3[e]);
                float wA = w_s[(k8 * 8 + e * 2) * 64 + col];
                float wB = w_s[(k8 * 8 + e * 2 + 1) * 64 + col];
                a0 = fmaf(g0.x, wA, a0); a0 = fmaf(g0.y, wB, a0);
                a1 = fmaf(g1.x, wA, a1); a1 = fmaf(g1.y, wB, a1);
                a2 = fmaf(g2.x, wA, a2); a2 = fmaf(g2.y, wB, a2);
                a3 = fmaf(g3.x, wA, a3); a3 = fmaf(g3.y, wB, a3);
            }
        }
        if (r0 + 3 < n) {
            size_t b = (size_t)r0 * 64 + col;
            h2[b]       = __float2half(a0);
            h2[b + 64]  = __float2half(a1);
            h2[b + 128] = __float2half(a2);
            h2[b + 192] = __float2half(a3);
        } else {
            float av[4] = {a0, a1, a2, a3};
            for (int r = 0; r < 4; ++r)
                if (r0 + r < n) h2[(size_t)(r0 + r) * 64 + col] = __float2half(av[r]);
        }
    }
}

// ---------------------------------------------------------------------------
// fused layer-1 softmax+aggregate+bias+relu + layer-2 logits.
// one block per dst node, wave == head. h1 gathered as fp16.
// ---------------------------------------------------------------------------
__global__ __launch_bounds__(256) void aggr1_csr(
    const int* __restrict__ rowptr, const int* __restrict__ deg,
    const int* __restrict__ csr_src,
    const float* __restrict__ a_s, const float* __restrict__ a_d,
    const __half* __restrict__ h1, const float* __restrict__ b1,
    const float* __restrict__ wa2s, const float* __restrict__ wa2d,
    __half* __restrict__ out1r, float* __restrict__ a_s2, float* __restrict__ a_d2,
    int n)
{
    __shared__ float al[4][64];
    __shared__ int   ss[64];
    __shared__ float ev[4][128];
    __shared__ float p1[4], p2[4];
    int t = blockIdx.x;
    int tid = threadIdx.x, h = tid >> 6, lane = tid & 63;
    int row0 = rowptr[t], d = deg[t];
    float adt = a_d[t * 4 + h];
    float w2s = wa2s[tid], w2d = wa2d[tid];
    bool small = (d <= 128);

    float m = -INFINITY;
    if (small) {
        for (int i = lane; i < d; i += 64) {
            float v = lrelu(a_s[csr_src[row0 + i] * 4 + h] + adt);
            ev[h][i] = v;
            m = fmaxf(m, v);
        }
    } else {
        for (int i = lane; i < d; i += 64)
            m = fmaxf(m, lrelu(a_s[csr_src[row0 + i] * 4 + h] + adt));
    }
    #pragma unroll
    for (int off = 32; off; off >>= 1) m = fmaxf(m, __shfl_xor(m, off));

    float dsum = 0.f;
    if (small) {
        for (int i = lane; i < d; i += 64) dsum += __expf(ev[h][i] - m);
    } else {
        for (int i = lane; i < d; i += 64)
            dsum += __expf(lrelu(a_s[csr_src[row0 + i] * 4 + h] + adt) - m);
    }
    #pragma unroll
    for (int off = 32; off; off >>= 1) dsum += __shfl_xor(dsum, off);
    float inv = (d > 0) ? 1.f / dsum : 0.f;

    float acc = 0.f;
    for (int c0 = 0; c0 < d; c0 += 64) {
        int i = c0 + lane;
        float alpha = 0.f;
        if (i < d) {
            float v = small ? ev[h][i] : lrelu(a_s[csr_src[row0 + i] * 4 + h] + adt);
            alpha = __expf(v - m) * inv;
        }
        al[h][lane] = alpha;
        if (h == 0) ss[lane] = (i < d) ? csr_src[row0 + i] * 256 : 0;
        __syncthreads();
        int cl = min(64, d - c0);
        const __half* hp = h1 + tid;
        int j = 0;
        for (; j + 4 <= cl; j += 4) {
            int o0 = ss[j], o1 = ss[j + 1], o2 = ss[j + 2], o3 = ss[j + 3];
            float b0 = al[h][j], c1 = al[h][j + 1], c2 = al[h][j + 2], c3 = al[h][j + 3];
            float v0 = __half2float(hp[o0]), v1 = __half2float(hp[o1]);
            float v2 = __half2float(hp[o2]), v3 = __half2float(hp[o3]);
            acc = fmaf(b0, v0, acc);
            acc = fmaf(c1, v1, acc);
            acc = fmaf(c2, v2, acc);
            acc = fmaf(c3, v3, acc);
        }
        for (; j < cl; ++j) acc = fmaf(al[h][j], __half2float(hp[ss[j]]), acc);
        __syncthreads();
    }

    float r = fmaxf(acc + b1[tid], 0.f);
    out1r[(size_t)t * 256 + tid] = __float2half(r);
    float s2 = r * w2s, d2v = r * w2d;
    #pragma unroll
    for (int off = 32; off; off >>= 1) {
        s2  += __shfl_down(s2, off);
        d2v += __shfl_down(d2v, off);
    }
    if (lane == 0) { p1[h] = s2; p2[h] = d2v; }
    __syncthreads();
    if (tid == 0) {
        a_s2[t] = p1[0] + p1[1] + p1[2] + p1[3];
        a_d2[t] = p2[0] + p2[1] + p2[2] + p2[3];
    }
}

// ---------------------------------------------------------------------------
// fused layer-2 softmax+aggregate: one wave per dst node, wave-private LDS,
// no barriers. h2 gathered as fp16.
// ---------------------------------------------------------------------------
__global__ __launch_bounds__(256) void aggr2_csr(
    const int* __restrict__ rowptr, const int* __restrict__ deg,
    const int* __restrict__ csr_src,
    const float* __restrict__ a_s, const float* __restrict__ a_d,
    const __half* __restrict__ h2, const float* __restrict__ b2,
    float* __restrict__ dout, int n)
{
    __shared__ float ev2[4][128];
    __shared__ float al2[4][64];
    __shared__ int   ss2[4][64];
    int wv = threadIdx.x >> 6, lane = threadIdx.x & 63;
    int t = blockIdx.x * 4 + wv;
    if (t >= n) return;
    int row0 = rowptr[t], d = deg[t];
    float adt = a_d[t];
    bool small = (d <= 128);

    float m = -INFINITY;
    if (small) {
        for (int i = lane; i < d; i += 64) {
            float v = lrelu(a_s[csr_src[row0 + i]] + adt);
            ev2[wv][i] = v;
            m = fmaxf(m, v);
        }
    } else {
        for (int i = lane; i < d; i += 64)
            m = fmaxf(m, lrelu(a_s[csr_src[row0 + i]] + adt));
    }
    #pragma unroll
    for (int off = 32; off; off >>= 1) m = fmaxf(m, __shfl_xor(m, off));

    float dsum = 0.f;
    if (small) {
        for (int i = lane; i < d; i += 64) dsum += __expf(ev2[wv][i] - m);
    } else {
        for (int i = lane; i < d; i += 64)
            dsum += __expf(lrelu(a_s[csr_src[row0 + i]] + adt) - m);
    }
    #pragma unroll
    for (int off = 32; off; off >>= 1) dsum += __shfl_xor(dsum, off);
    float inv = (d > 0) ? 1.f / dsum : 0.f;

    float acc = 0.f;
    for (int c0 = 0; c0 < d; c0 += 64) {
        int i = c0 + lane;
        float alpha = 0.f; int so = 0;
        if (i < d) {
            int s = csr_src[row0 + i];
            so = s * 64;
            float v = small ? ev2[wv][i] : lrelu(a_s[s] + adt);
            alpha = __expf(v - m) * inv;
        }
        al2[wv][lane] = alpha;
        ss2[wv][lane] = so;
        int cl = min(64, d - c0);
        const __half* hp = h2 + lane;
        int j = 0;
        for (; j + 4 <= cl; j += 4) {
            int o0 = ss2[wv][j], o1 = ss2[wv][j + 1], o2 = ss2[wv][j + 2], o3 = ss2[wv][j + 3];
            float b0 = al2[wv][j], c1 = al2[wv][j + 1], c2 = al2[wv][j + 2], c3 = al2[wv][j + 3];
            float v0 = __half2float(hp[o0]), v1 = __half2float(hp[o1]);
            float v2 = __half2float(hp[o2]), v3 = __half2float(hp[o3]);
            acc = fmaf(b0, v0, acc);
            acc = fmaf(c1, v1, acc);
            acc = fmaf(c2, v2, acc);
            acc = fmaf(c3, v3, acc);
        }
        for (; j < cl; ++j) acc = fmaf(al2[wv][j], __half2float(hp[ss2[wv][j]]), acc);
    }
    dout[(size_t)t * 64 + lane] = acc + b2[lane];
}

// ---------------------------------------------------------------------------
extern "C" void kernel_launch(void* const* d_in, const int* in_sizes, int n_in,
                              void* d_out, int out_size, void* d_ws, size_t ws_size,
                              hipStream_t stream)
{
    const float* x    = (const float*)d_in[0];
    const int*   ei   = (const int*)d_in[1];
    const float* W1   = (const float*)d_in[2];
    const float* as1  = (const float*)d_in[3];
    const float* ad1  = (const float*)d_in[4];
    const float* b1   = (const float*)d_in[5];
    const float* W2   = (const float*)d_in[6];
    const float* as2  = (const float*)d_in[7];
    const float* ad2  = (const float*)d_in[8];
    const float* b2   = (const float*)d_in[9];
    float* dout = (float*)d_out;

    const int n  = in_sizes[0] / H_IN;        // 50000
    const int ne = in_sizes[1] / 2;           // 800000
    const int* src = ei;
    const int* dst = ei + ne;
    const int NB = (n + 255) / 256;           // 196

    float* ws = (float*)d_ws;
    __half* h1h   = (__half*)ws;                    // n*256 halves; reused as h2
    __half* out1r = h1h + (size_t)n * 256;          // n*256 halves
    float* fbase  = ws + (size_t)n * 256;           // after the two half arrays
    float* a_s1   = fbase;                          // n*4
    float* a_d1   = a_s1   + (size_t)n * 4;         // n*4
    float* a_s2   = a_d1   + (size_t)n * 4;         // n
    float* a_d2   = a_s2   + (size_t)n;             // n
    float* wa1s   = a_d2   + (size_t)n;             // 256
    float* wa1d   = wa1s + 256;                     // 256
    float* wa2s   = wa1d + 256;                     // 256
    float* wa2d   = wa2s + 256;                     // 256
    int*   deg    = (int*)(wa2d + 256);             // n
    int*   rowptr = deg + n;                        // n
    int*   csr    = rowptr + n;                     // ne
    int*   bsum   = csr + ne;                       // NB
    int*   bpre   = bsum + NB;                      // NB
    int*   cursor = (int*)h1h;                      // n ints (dead before gemm1 writes h1)
    __half* h2h   = h1h;                            // n*64 halves (h1 dead after aggr1)

    // ---- precompute W·att ----
    micro_wa<<<1, 256, 0, stream>>>(W1, as1, ad1, W2, as2, ad2, wa1s, wa1d, wa2s, wa2d);

    // ---- CSR build ----
    zero_int2<<<NB, 256, 0, stream>>>(deg, cursor, n);
    hist_kernel<<<(ne + 255) / 256, 256, 0, stream>>>(dst, deg, ne);
    block_sum<<<NB, 256, 0, stream>>>(deg, bsum, n);
    scan_bsum<<<1, 256, 0, stream>>>(bsum, bpre, NB);
    scan_rowptr<<<NB, 256, 0, stream>>>(deg, bpre, rowptr, n);
    scatter_kernel<<<(ne + 255) / 256, 256, 0, stream>>>(src, dst, rowptr, cursor, csr, ne);

    // ---- layer 1 ----
    axw1_kernel<<<NB, 256, 0, stream>>>(x, wa1s, wa1d, a_s1, a_d1, n);
    gemm1_kernel<<<n / 16, 256, 0, stream>>>(x, W1, h1h, n);
    aggr1_csr<<<n, 256, 0, stream>>>(rowptr, deg, csr, a_s1, a_d1, h1h, b1,
                                     wa2s, wa2d, out1r, a_s2, a_d2, n);

    // ---- layer 2 ----
    gemm2_kernel<<<(n + 63) / 64, 256, 0, stream>>>(out1r, W2, h2h, n);
    aggr2_csr<<<(n + 3) / 4, 256, 0, stream>>>(rowptr, deg, csr, a_s2, a_d2, h2h, b2, dout, n);
}

// Round 9
// 443.120 us; speedup vs baseline: 3.4541x; 1.1196x over previous
//
#include <hip/hip_runtime.h>
#include <hip/hip_fp16.h>

#define NEG_SLOPE 0.2f
#define H_IN 64

__device__ __forceinline__ float lrelu(float v) { return v > 0.f ? v : NEG_SLOPE * v; }

// ---------------------------------------------------------------------------
// CSR build: zero -> hist -> block_sum -> scan_bsum -> scan_rowptr -> scatter
// ---------------------------------------------------------------------------
__global__ __launch_bounds__(256) void zero_int2(int* __restrict__ a,
                                                 int* __restrict__ b, int n)
{
    int i = blockIdx.x * 256 + threadIdx.x;
    if (i < n) { a[i] = 0; b[i] = 0; }
}

__global__ __launch_bounds__(256) void hist_kernel(const int* __restrict__ dst,
                                                   int* __restrict__ deg, int ne)
{
    int e = blockIdx.x * 256 + threadIdx.x;
    if (e < ne) atomicAdd(&deg[dst[e]], 1);
}

__global__ __launch_bounds__(256) void block_sum(const int* __restrict__ deg,
                                                 int* __restrict__ bsum, int n)
{
    __shared__ int part[4];
    int i = blockIdx.x * 256 + threadIdx.x;
    int v = (i < n) ? deg[i] : 0;
    #pragma unroll
    for (int off = 32; off; off >>= 1) v += __shfl_down(v, off);
    int lane = threadIdx.x & 63, wv = threadIdx.x >> 6;
    if (lane == 0) part[wv] = v;
    __syncthreads();
    if (threadIdx.x == 0)
        bsum[blockIdx.x] = part[0] + part[1] + part[2] + part[3];
}

__global__ __launch_bounds__(256) void scan_bsum(const int* __restrict__ bsum,
                                                 int* __restrict__ bpre, int nb)
{
    __shared__ int sm[256];
    int t = threadIdx.x;
    int v = (t < nb) ? bsum[t] : 0;
    sm[t] = v; __syncthreads();
    for (int off = 1; off < 256; off <<= 1) {
        int y = (t >= off) ? sm[t - off] : 0;
        __syncthreads();
        if (t >= off) sm[t] += y;
        __syncthreads();
    }
    if (t < nb) bpre[t] = sm[t] - v;   // exclusive
}

__global__ __launch_bounds__(256) void scan_rowptr(const int* __restrict__ deg,
                                                   const int* __restrict__ bpre,
                                                   int* __restrict__ rowptr, int n)
{
    __shared__ int sm[256];
    int t = threadIdx.x;
    int i = blockIdx.x * 256 + t;
    int v = (i < n) ? deg[i] : 0;
    sm[t] = v; __syncthreads();
    for (int off = 1; off < 256; off <<= 1) {
        int y = (t >= off) ? sm[t - off] : 0;
        __syncthreads();
        if (t >= off) sm[t] += y;
        __syncthreads();
    }
    if (i < n) rowptr[i] = sm[t] - v + bpre[blockIdx.x];
}

__global__ __launch_bounds__(256) void scatter_kernel(
    const int* __restrict__ src, const int* __restrict__ dst,
    const int* __restrict__ rowptr, int* __restrict__ cursor,
    int* __restrict__ csr_src, int ne)
{
    int e = blockIdx.x * 256 + threadIdx.x;
    if (e >= ne) return;
    int t = dst[e];
    int pos = atomicAdd(&cursor[t], 1);
    csr_src[rowptr[t] + pos] = src[e];
}

// ---------------------------------------------------------------------------
// micro: wa1s/wa1d[k*4+h] = sum_c W1[k,h*64+c]*att1[h,c];  wa2s/wa2d[k] likewise
// ---------------------------------------------------------------------------
__global__ __launch_bounds__(256) void micro_wa(
    const float* __restrict__ W1, const float* __restrict__ as1, const float* __restrict__ ad1,
    const float* __restrict__ W2, const float* __restrict__ as2, const float* __restrict__ ad2,
    float* __restrict__ wa1s, float* __restrict__ wa1d,
    float* __restrict__ wa2s, float* __restrict__ wa2d)
{
    int tid = threadIdx.x;
    int k = tid >> 2, h = tid & 3;
    float s = 0.f, d = 0.f;
    #pragma unroll 8
    for (int c = 0; c < 64; ++c) {
        float w = W1[k * 256 + h * 64 + c];
        s = fmaf(w, as1[h * 64 + c], s);
        d = fmaf(w, ad1[h * 64 + c], d);
    }
    wa1s[k * 4 + h] = s; wa1d[k * 4 + h] = d;
    float s2 = 0.f, d2 = 0.f;
    #pragma unroll 8
    for (int c = 0; c < 64; ++c) {
        float w = W2[tid * 64 + c];
        s2 = fmaf(w, as2[c], s2);
        d2 = fmaf(w, ad2[c], d2);
    }
    wa2s[tid] = s2; wa2d[tid] = d2;
}

// ---------------------------------------------------------------------------
// axw1: a_s1[row,h] = sum_k x[row,k]*wa1s[k,h]  (and a_d1)
// ---------------------------------------------------------------------------
__global__ __launch_bounds__(256) void axw1_kernel(
    const float* __restrict__ x,
    const float* __restrict__ wa1s, const float* __restrict__ wa1d,
    float* __restrict__ a_s, float* __restrict__ a_d, int n)
{
    __shared__ float ws[256], wd[256];
    int tid = threadIdx.x;
    ws[tid] = wa1s[tid]; wd[tid] = wa1d[tid];
    __syncthreads();
    int row = blockIdx.x * 256 + tid;
    if (row >= n) return;
    const float4* xv = (const float4*)(x + (size_t)row * 64);
    float aS[4] = {0, 0, 0, 0}, aD[4] = {0, 0, 0, 0};
    #pragma unroll
    for (int k4 = 0; k4 < 16; ++k4) {
        float4 q = xv[k4];
        float xe[4] = {q.x, q.y, q.z, q.w};
        #pragma unroll
        for (int e = 0; e < 4; ++e) {
            int k = k4 * 4 + e;
            #pragma unroll
            for (int h = 0; h < 4; ++h) {
                aS[h] = fmaf(xe[e], ws[k * 4 + h], aS[h]);
                aD[h] = fmaf(xe[e], wd[k * 4 + h], aD[h]);
            }
        }
    }
    #pragma unroll
    for (int h = 0; h < 4; ++h) {
        a_s[row * 4 + h] = aS[h];
        a_d[row * 4 + h] = aD[h];
    }
}

// ---------------------------------------------------------------------------
// gemm1: h1[N,256] (fp16) = x[N,64] @ W1[64,256]; 16 rows/block.
// K-chunked LDS (2 x 32KB phases) -> 4-5 blocks/CU occupancy.
// ---------------------------------------------------------------------------
__global__ __launch_bounds__(256) void gemm1_kernel(
    const float* __restrict__ x, const float* __restrict__ W1,
    __half* __restrict__ h1, int n)
{
    __shared__ float w_s[32 * 256];          // 32 KB
    int tid = threadIdx.x;
    int row0 = blockIdx.x * 16;              // n divisible by 16
    float acc[4][4];
    #pragma unroll
    for (int s = 0; s < 4; ++s)
        #pragma unroll
        for (int r = 0; r < 4; ++r) acc[s][r] = 0.f;

    const float4* Wv = (const float4*)W1;
    for (int kk = 0; kk < 2; ++kk) {
        if (kk) __syncthreads();
        {
            float4* wv = (float4*)w_s;
            #pragma unroll
            for (int i = 0; i < 8; ++i)
                wv[tid + i * 256] = Wv[kk * 2048 + tid + i * 256];
        }
        __syncthreads();
        #pragma unroll
        for (int sub = 0; sub < 4; ++sub) {
            const float4* x0 = (const float4*)(x + (size_t)(row0 + sub * 4) * 64 + kk * 32);
            const float4* x1 = x0 + 16;      // fp32 row = 16 float4
            const float4* x2 = x0 + 32;
            const float4* x3 = x0 + 48;
            #pragma unroll
            for (int k4 = 0; k4 < 8; ++k4) {
                float4 q0 = x0[k4], q1 = x1[k4], q2 = x2[k4], q3 = x3[k4];
                const float* f0 = (const float*)&q0;
                const float* f1 = (const float*)&q1;
                const float* f2 = (const float*)&q2;
                const float* f3 = (const float*)&q3;
                #pragma unroll
                for (int e = 0; e < 4; ++e) {
                    float w = w_s[(k4 * 4 + e) * 256 + tid];
                    acc[sub][0] = fmaf(f0[e], w, acc[sub][0]);
                    acc[sub][1] = fmaf(f1[e], w, acc[sub][1]);
                    acc[sub][2] = fmaf(f2[e], w, acc[sub][2]);
                    acc[sub][3] = fmaf(f3[e], w, acc[sub][3]);
                }
            }
        }
    }
    #pragma unroll
    for (int sub = 0; sub < 4; ++sub) {
        size_t base = (size_t)(row0 + sub * 4) * 256 + tid;
        h1[base]       = __float2half(acc[sub][0]);
        h1[base + 256] = __float2half(acc[sub][1]);
        h1[base + 512] = __float2half(acc[sub][2]);
        h1[base + 768] = __float2half(acc[sub][3]);
    }
}

// ---------------------------------------------------------------------------
// gemm2: h2[N,64] (fp16) = out1r[N,256] (fp16) @ W2[256,64]; 64 rows/block
// (16/wave). K-chunked LDS (2 x 32KB). fp16 row = 32 float4.
// ---------------------------------------------------------------------------
__global__ __launch_bounds__(256) void gemm2_kernel(
    const __half* __restrict__ xr, const float* __restrict__ W2,
    __half* __restrict__ h2, int n)
{
    __shared__ float w_s[128 * 64];          // 32 KB
    int tid = threadIdx.x;
    int col = tid & 63, wv_ = tid >> 6;
    int row0 = blockIdx.x * 64 + wv_ * 16;
    float acc[4][4];
    #pragma unroll
    for (int s = 0; s < 4; ++s)
        #pragma unroll
        for (int r = 0; r < 4; ++r) acc[s][r] = 0.f;

    const float4* Wv = (const float4*)W2;
    for (int kk = 0; kk < 2; ++kk) {
        if (kk) __syncthreads();
        {
            float4* wv = (float4*)w_s;
            #pragma unroll
            for (int i = 0; i < 8; ++i)
                wv[tid + i * 256] = Wv[kk * 2048 + tid + i * 256];
        }
        __syncthreads();
        #pragma unroll
        for (int sub = 0; sub < 4; ++sub) {
            int r0 = row0 + sub * 4;
            const float4* x0 = (const float4*)(xr + (size_t)r0 * 256 + kk * 128);
            const float4* x1 = x0 + 32;      // fp16 row = 32 float4
            const float4* x2 = x0 + 64;
            const float4* x3 = x0 + 96;
            #pragma unroll 4
            for (int k8 = 0; k8 < 16; ++k8) {
                float4 q0 = x0[k8], q1 = x1[k8], q2 = x2[k8], q3 = x3[k8];
                const __half2* p0 = (const __half2*)&q0;
                const __half2* p1 = (const __half2*)&q1;
                const __half2* p2 = (const __half2*)&q2;
                const __half2* p3 = (const __half2*)&q3;
                #pragma unroll
                for (int e = 0; e < 4; ++e) {
                    float2 g0 = __half22float2(p0[e]);
                    float2 g1 = __half22float2(p1[e]);
                    float2 g2 = __half22float2(p2[e]);
                    float2 g3 = __half22float2(p3[e]);
                    float wA = w_s[(k8 * 8 + e * 2) * 64 + col];
                    float wB = w_s[(k8 * 8 + e * 2 + 1) * 64 + col];
                    acc[sub][0] = fmaf(g0.x, wA, acc[sub][0]); acc[sub][0] = fmaf(g0.y, wB, acc[sub][0]);
                    acc[sub][1] = fmaf(g1.x, wA, acc[sub][1]); acc[sub][1] = fmaf(g1.y, wB, acc[sub][1]);
                    acc[sub][2] = fmaf(g2.x, wA, acc[sub][2]); acc[sub][2] = fmaf(g2.y, wB, acc[sub][2]);
                    acc[sub][3] = fmaf(g3.x, wA, acc[sub][3]); acc[sub][3] = fmaf(g3.y, wB, acc[sub][3]);
                }
            }
        }
    }
    #pragma unroll
    for (int sub = 0; sub < 4; ++sub) {
        int r0 = row0 + sub * 4;
        if (r0 + 3 < n) {
            size_t b = (size_t)r0 * 64 + col;
            h2[b]       = __float2half(acc[sub][0]);
            h2[b + 64]  = __float2half(acc[sub][1]);
            h2[b + 128] = __float2half(acc[sub][2]);
            h2[b + 192] = __float2half(acc[sub][3]);
        } else {
            for (int r = 0; r < 4; ++r)
                if (r0 + r < n) h2[(size_t)(r0 + r) * 64 + col] = __float2half(acc[sub][r]);
        }
    }
}

// ---------------------------------------------------------------------------
// fused layer-1 softmax+aggregate+bias+relu + layer-2 logits.
// one block per dst node. Softmax phase: wave == head.
// Gather phase: thread owns __half2 channel pair (cpair=tid&127) and
// edge slot p=tid>>7 (2 edges in flight); partials merged via LDS.
// ---------------------------------------------------------------------------
__global__ __launch_bounds__(256) void aggr1_csr(
    const int* __restrict__ rowptr, const int* __restrict__ deg,
    const int* __restrict__ csr_src,
    const float* __restrict__ a_s, const float* __restrict__ a_d,
    const __half* __restrict__ h1, const float* __restrict__ b1,
    const float* __restrict__ wa2s, const float* __restrict__ wa2d,
    __half* __restrict__ out1r, float* __restrict__ a_s2, float* __restrict__ a_d2,
    int n)
{
    __shared__ float al[4][64];
    __shared__ int   ss[64];
    __shared__ float ev[4][128];
    __shared__ float2 pm[128];
    __shared__ float p1[2], p2[2];
    int t = blockIdx.x;
    int tid = threadIdx.x, h = tid >> 6, lane = tid & 63;
    int row0 = rowptr[t], d = deg[t];
    float adt = a_d[t * 4 + h];
    bool small = (d <= 128);

    float m = -INFINITY;
    if (small) {
        for (int i = lane; i < d; i += 64) {
            float v = lrelu(a_s[csr_src[row0 + i] * 4 + h] + adt);
            ev[h][i] = v;
            m = fmaxf(m, v);
        }
    } else {
        for (int i = lane; i < d; i += 64)
            m = fmaxf(m, lrelu(a_s[csr_src[row0 + i] * 4 + h] + adt));
    }
    #pragma unroll
    for (int off = 32; off; off >>= 1) m = fmaxf(m, __shfl_xor(m, off));

    float dsum = 0.f;
    if (small) {
        for (int i = lane; i < d; i += 64) dsum += __expf(ev[h][i] - m);
    } else {
        for (int i = lane; i < d; i += 64)
            dsum += __expf(lrelu(a_s[csr_src[row0 + i] * 4 + h] + adt) - m);
    }
    #pragma unroll
    for (int off = 32; off; off >>= 1) dsum += __shfl_xor(dsum, off);
    float inv = (d > 0) ? 1.f / dsum : 0.f;

    int cpair = tid & 127;       // half2 channel pair 0..127
    int p = tid >> 7;            // edge slot 0/1
    int hc = cpair >> 5;         // head of this pair
    float2 acc = make_float2(0.f, 0.f);
    const __half2* hbase = (const __half2*)h1;

    for (int c0 = 0; c0 < d; c0 += 64) {
        int i = c0 + lane;
        float alpha = 0.f;
        if (i < d) {
            float v = small ? ev[h][i] : lrelu(a_s[csr_src[row0 + i] * 4 + h] + adt);
            alpha = __expf(v - m) * inv;
        }
        al[h][lane] = alpha;
        if (h == 0) ss[lane] = (i < d) ? csr_src[row0 + i] * 128 : 0;  // half2-row offset
        __syncthreads();
        int cl = min(64, d - c0);
        int j = p;
        for (; j + 2 < cl; j += 4) {
            float a0 = al[hc][j];
            float a1 = al[hc][j + 2];
            float2 g0 = __half22float2(hbase[ss[j] + cpair]);
            float2 g1 = __half22float2(hbase[ss[j + 2] + cpair]);
            acc.x = fmaf(a0, g0.x, acc.x);
            acc.y = fmaf(a0, g0.y, acc.y);
            acc.x = fmaf(a1, g1.x, acc.x);
            acc.y = fmaf(a1, g1.y, acc.y);
        }
        if (j < cl) {
            float a0 = al[hc][j];
            float2 g0 = __half22float2(hbase[ss[j] + cpair]);
            acc.x = fmaf(a0, g0.x, acc.x);
            acc.y = fmaf(a0, g0.y, acc.y);
        }
        __syncthreads();
    }

    // merge the two edge slots
    if (p == 1) pm[cpair] = acc;
    __syncthreads();
    if (p == 0) {
        float2 o = pm[cpair];
        float r0v = fmaxf(acc.x + o.x + b1[2 * cpair], 0.f);
        float r1v = fmaxf(acc.y + o.y + b1[2 * cpair + 1], 0.f);
        ((__half2*)out1r)[(size_t)t * 128 + cpair] = __floats2half2_rn(r0v, r1v);
        float s2  = r0v * wa2s[2 * cpair] + r1v * wa2s[2 * cpair + 1];
        float d2v = r0v * wa2d[2 * cpair] + r1v * wa2d[2 * cpair + 1];
        #pragma unroll
        for (int off = 32; off; off >>= 1) {
            s2  += __shfl_down(s2, off);
            d2v += __shfl_down(d2v, off);
        }
        if ((tid & 63) == 0) { p1[tid >> 6] = s2; p2[tid >> 6] = d2v; }
    }
    __syncthreads();
    if (tid == 0) {
        a_s2[t] = p1[0] + p1[1];
        a_d2[t] = p2[0] + p2[1];
    }
}

// ---------------------------------------------------------------------------
// fused layer-2 softmax+aggregate: one wave per dst node, wave-private LDS.
// Gather: lanes 0-31 own half2 channel pairs, lane>>5 = edge slot (2 edges
// in flight); slots merged by shfl_down 32.
// ---------------------------------------------------------------------------
__global__ __launch_bounds__(256) void aggr2_csr(
    const int* __restrict__ rowptr, const int* __restrict__ deg,
    const int* __restrict__ csr_src,
    const float* __restrict__ a_s, const float* __restrict__ a_d,
    const __half* __restrict__ h2, const float* __restrict__ b2,
    float* __restrict__ dout, int n)
{
    __shared__ float ev2[4][128];
    __shared__ float al2[4][64];
    __shared__ int   ss2[4][64];
    int wv = threadIdx.x >> 6, lane = threadIdx.x & 63;
    int t = blockIdx.x * 4 + wv;
    if (t >= n) return;
    int row0 = rowptr[t], d = deg[t];
    float adt = a_d[t];
    bool small = (d <= 128);

    float m = -INFINITY;
    if (small) {
        for (int i = lane; i < d; i += 64) {
            float v = lrelu(a_s[csr_src[row0 + i]] + adt);
            ev2[wv][i] = v;
            m = fmaxf(m, v);
        }
    } else {
        for (int i = lane; i < d; i += 64)
            m = fmaxf(m, lrelu(a_s[csr_src[row0 + i]] + adt));
    }
    #pragma unroll
    for (int off = 32; off; off >>= 1) m = fmaxf(m, __shfl_xor(m, off));

    float dsum = 0.f;
    if (small) {
        for (int i = lane; i < d; i += 64) dsum += __expf(ev2[wv][i] - m);
    } else {
        for (int i = lane; i < d; i += 64)
            dsum += __expf(lrelu(a_s[csr_src[row0 + i]] + adt) - m);
    }
    #pragma unroll
    for (int off = 32; off; off >>= 1) dsum += __shfl_xor(dsum, off);
    float inv = (d > 0) ? 1.f / dsum : 0.f;

    int c2 = lane & 31;          // half2 channel pair 0..31
    int p = lane >> 5;           // edge slot
    float2 acc = make_float2(0.f, 0.f);
    const __half2* hbase = (const __half2*)h2;

    for (int c0 = 0; c0 < d; c0 += 64) {
        int i = c0 + lane;
        float alpha = 0.f; int so = 0;
        if (i < d) {
            int s = csr_src[row0 + i];
            so = s * 32;                    // half2-row offset (64 halves)
            float v = small ? ev2[wv][i] : lrelu(a_s[s] + adt);
            alpha = __expf(v - m) * inv;
        }
        al2[wv][lane] = alpha;
        ss2[wv][lane] = so;
        int cl = min(64, d - c0);
        int j = p;
        for (; j + 2 < cl; j += 4) {
            float a0 = al2[wv][j];
            float a1 = al2[wv][j + 2];
            float2 g0 = __half22float2(hbase[ss2[wv][j] + c2]);
            float2 g1 = __half22float2(hbase[ss2[wv][j + 2] + c2]);
            acc.x = fmaf(a0, g0.x, acc.x);
            acc.y = fmaf(a0, g0.y, acc.y);
            acc.x = fmaf(a1, g1.x, acc.x);
            acc.y = fmaf(a1, g1.y, acc.y);
        }
        if (j < cl) {
            float a0 = al2[wv][j];
            float2 g0 = __half22float2(hbase[ss2[wv][j] + c2]);
            acc.x = fmaf(a0, g0.x, acc.x);
            acc.y = fmaf(a0, g0.y, acc.y);
        }
    }

    acc.x += __shfl_down(acc.x, 32);
    acc.y += __shfl_down(acc.y, 32);
    if (p == 0) {
        float2 o;
        o.x = acc.x + b2[2 * c2];
        o.y = acc.y + b2[2 * c2 + 1];
        ((float2*)(dout + (size_t)t * 64))[c2] = o;
    }
}

// ---------------------------------------------------------------------------
extern "C" void kernel_launch(void* const* d_in, const int* in_sizes, int n_in,
                              void* d_out, int out_size, void* d_ws, size_t ws_size,
                              hipStream_t stream)
{
    const float* x    = (const float*)d_in[0];
    const int*   ei   = (const int*)d_in[1];
    const float* W1   = (const float*)d_in[2];
    const float* as1  = (const float*)d_in[3];
    const float* ad1  = (const float*)d_in[4];
    const float* b1   = (const float*)d_in[5];
    const float* W2   = (const float*)d_in[6];
    const float* as2  = (const float*)d_in[7];
    const float* ad2  = (const float*)d_in[8];
    const float* b2   = (const float*)d_in[9];
    float* dout = (float*)d_out;

    const int n  = in_sizes[0] / H_IN;        // 50000
    const int ne = in_sizes[1] / 2;           // 800000
    const int* src = ei;
    const int* dst = ei + ne;
    const int NB = (n + 255) / 256;           // 196

    float* ws = (float*)d_ws;
    __half* h1h   = (__half*)ws;                    // n*256 halves; reused as h2
    __half* out1r = h1h + (size_t)n * 256;          // n*256 halves
    float* fbase  = ws + (size_t)n * 256;           // after the two half arrays
    float* a_s1   = fbase;                          // n*4
    float* a_d1   = a_s1   + (size_t)n * 4;         // n*4
    float* a_s2   = a_d1   + (size_t)n * 4;         // n
    float* a_d2   = a_s2   + (size_t)n;             // n
    float* wa1s   = a_d2   + (size_t)n;             // 256
    float* wa1d   = wa1s + 256;                     // 256
    float* wa2s   = wa1d + 256;                     // 256
    float* wa2d   = wa2s + 256;                     // 256
    int*   deg    = (int*)(wa2d + 256);             // n
    int*   rowptr = deg + n;                        // n
    int*   csr    = rowptr + n;                     // ne
    int*   bsum   = csr + ne;                       // NB
    int*   bpre   = bsum + NB;                      // NB
    int*   cursor = (int*)h1h;                      // n ints (dead before gemm1 writes h1)
    __half* h2h   = h1h;                            // n*64 halves (h1 dead after aggr1)

    // ---- precompute W·att ----
    micro_wa<<<1, 256, 0, stream>>>(W1, as1, ad1, W2, as2, ad2, wa1s, wa1d, wa2s, wa2d);

    // ---- CSR build ----
    zero_int2<<<NB, 256, 0, stream>>>(deg, cursor, n);
    hist_kernel<<<(ne + 255) / 256, 256, 0, stream>>>(dst, deg, ne);
    block_sum<<<NB, 256, 0, stream>>>(deg, bsum, n);
    scan_bsum<<<1, 256, 0, stream>>>(bsum, bpre, NB);
    scan_rowptr<<<NB, 256, 0, stream>>>(deg, bpre, rowptr, n);
    scatter_kernel<<<(ne + 255) / 256, 256, 0, stream>>>(src, dst, rowptr, cursor, csr, ne);

    // ---- layer 1 ----
    axw1_kernel<<<NB, 256, 0, stream>>>(x, wa1s, wa1d, a_s1, a_d1, n);
    gemm1_kernel<<<n / 16, 256, 0, stream>>>(x, W1, h1h, n);
    aggr1_csr<<<n, 256, 0, stream>>>(rowptr, deg, csr, a_s1, a_d1, h1h, b1,
                                     wa2s, wa2d, out1r, a_s2, a_d2, n);

    // ---- layer 2 ----
    gemm2_kernel<<<(n + 63) / 64, 256, 0, stream>>>(out1r, W2, h2h, n);
    aggr2_csr<<<(n + 3) / 4, 256, 0, stream>>>(rowptr, deg, csr, a_s2, a_d2, h2h, b2, dout, n);
}

// Round 10
// 426.257 us; speedup vs baseline: 3.5908x; 1.0396x over previous
//
#include <hip/hip_runtime.h>
#include <hip/hip_fp16.h>

#define NEG_SLOPE 0.2f
#define H_IN 64

typedef _Float16 h2vec __attribute__((ext_vector_type(2)));

__device__ __forceinline__ float lrelu(float v) { return v > 0.f ? v : NEG_SLOPE * v; }

__device__ __forceinline__ void cvt4(uint2 g, float* o) {
    __half2 lo = *(__half2*)&g.x, hi = *(__half2*)&g.y;
    float2 a = __half22float2(lo), b = __half22float2(hi);
    o[0] = a.x; o[1] = a.y; o[2] = b.x; o[3] = b.y;
}

__device__ __forceinline__ float fdot2h(float xf, h2vec w, float acc) {
#if __has_builtin(__builtin_amdgcn_fdot2)
    union { float f; h2vec h; } cv; cv.f = xf;
    return __builtin_amdgcn_fdot2(cv.h, w, acc, false);
#else
    union { float f; __half2 h; } cv; cv.f = xf;
    float2 g = __half22float2(cv.h);
    acc = fmaf(g.x, (float)w[0], acc);
    return fmaf(g.y, (float)w[1], acc);
#endif
}

// ---------------------------------------------------------------------------
// zero + micro fused: blocks 1..NB zero deg/cursor; block 0 computes W·att.
// ---------------------------------------------------------------------------
__global__ __launch_bounds__(256) void zero_micro(
    int* __restrict__ deg, int* __restrict__ cursor, int n,
    const float* __restrict__ W1, const float* __restrict__ as1, const float* __restrict__ ad1,
    const float* __restrict__ W2, const float* __restrict__ as2, const float* __restrict__ ad2,
    float* __restrict__ wa1s, float* __restrict__ wa1d,
    float* __restrict__ wa2s, float* __restrict__ wa2d)
{
    int tid = threadIdx.x;
    if (blockIdx.x > 0) {
        int i = (blockIdx.x - 1) * 256 + tid;
        if (i < n) { deg[i] = 0; cursor[i] = 0; }
        return;
    }
    int k = tid >> 2, h = tid & 3;
    float s = 0.f, d = 0.f;
    #pragma unroll 8
    for (int c = 0; c < 64; ++c) {
        float w = W1[k * 256 + h * 64 + c];
        s = fmaf(w, as1[h * 64 + c], s);
        d = fmaf(w, ad1[h * 64 + c], d);
    }
    wa1s[k * 4 + h] = s; wa1d[k * 4 + h] = d;
    float s2 = 0.f, d2 = 0.f;
    #pragma unroll 8
    for (int c = 0; c < 64; ++c) {
        float w = W2[tid * 64 + c];
        s2 = fmaf(w, as2[c], s2);
        d2 = fmaf(w, ad2[c], d2);
    }
    wa2s[tid] = s2; wa2d[tid] = d2;
}

__global__ __launch_bounds__(256) void hist_kernel(const int* __restrict__ dst,
                                                   int* __restrict__ deg, int ne)
{
    int e = blockIdx.x * 256 + threadIdx.x;
    if (e < ne) atomicAdd(&deg[dst[e]], 1);
}

__global__ __launch_bounds__(256) void block_sum(const int* __restrict__ deg,
                                                 int* __restrict__ bsum, int n)
{
    __shared__ int part[4];
    int i = blockIdx.x * 256 + threadIdx.x;
    int v = (i < n) ? deg[i] : 0;
    #pragma unroll
    for (int off = 32; off; off >>= 1) v += __shfl_down(v, off);
    int lane = threadIdx.x & 63, wv = threadIdx.x >> 6;
    if (lane == 0) part[wv] = v;
    __syncthreads();
    if (threadIdx.x == 0)
        bsum[blockIdx.x] = part[0] + part[1] + part[2] + part[3];
}

__global__ __launch_bounds__(256) void scan_bsum(const int* __restrict__ bsum,
                                                 int* __restrict__ bpre, int nb)
{
    __shared__ int sm[256];
    int t = threadIdx.x;
    int v = (t < nb) ? bsum[t] : 0;
    sm[t] = v; __syncthreads();
    for (int off = 1; off < 256; off <<= 1) {
        int y = (t >= off) ? sm[t - off] : 0;
        __syncthreads();
        if (t >= off) sm[t] += y;
        __syncthreads();
    }
    if (t < nb) bpre[t] = sm[t] - v;   // exclusive
}

__global__ __launch_bounds__(256) void scan_rowptr(const int* __restrict__ deg,
                                                   const int* __restrict__ bpre,
                                                   int* __restrict__ rowptr, int n)
{
    __shared__ int sm[256];
    int t = threadIdx.x;
    int i = blockIdx.x * 256 + t;
    int v = (i < n) ? deg[i] : 0;
    sm[t] = v; __syncthreads();
    for (int off = 1; off < 256; off <<= 1) {
        int y = (t >= off) ? sm[t - off] : 0;
        __syncthreads();
        if (t >= off) sm[t] += y;
        __syncthreads();
    }
    if (i < n) rowptr[i] = sm[t] - v + bpre[blockIdx.x];
}

__global__ __launch_bounds__(256) void scatter_kernel(
    const int* __restrict__ src, const int* __restrict__ dst,
    const int* __restrict__ rowptr, int* __restrict__ cursor,
    int* __restrict__ csr_src, int ne)
{
    int e = blockIdx.x * 256 + threadIdx.x;
    if (e >= ne) return;
    int t = dst[e];
    int pos = atomicAdd(&cursor[t], 1);
    csr_src[rowptr[t] + pos] = src[e];
}

// ---------------------------------------------------------------------------
// axw1: a_s1[row,h] = sum_k x[row,k]*wa1s[k,h]  (and a_d1)
// ---------------------------------------------------------------------------
__global__ __launch_bounds__(256) void axw1_kernel(
    const float* __restrict__ x,
    const float* __restrict__ wa1s, const float* __restrict__ wa1d,
    float* __restrict__ a_s, float* __restrict__ a_d, int n)
{
    __shared__ float ws[256], wd[256];
    int tid = threadIdx.x;
    ws[tid] = wa1s[tid]; wd[tid] = wa1d[tid];
    __syncthreads();
    int row = blockIdx.x * 256 + tid;
    if (row >= n) return;
    const float4* xv = (const float4*)(x + (size_t)row * 64);
    float aS[4] = {0, 0, 0, 0}, aD[4] = {0, 0, 0, 0};
    #pragma unroll
    for (int k4 = 0; k4 < 16; ++k4) {
        float4 q = xv[k4];
        float xe[4] = {q.x, q.y, q.z, q.w};
        #pragma unroll
        for (int e = 0; e < 4; ++e) {
            int k = k4 * 4 + e;
            #pragma unroll
            for (int h = 0; h < 4; ++h) {
                aS[h] = fmaf(xe[e], ws[k * 4 + h], aS[h]);
                aD[h] = fmaf(xe[e], wd[k * 4 + h], aD[h]);
            }
        }
    }
    #pragma unroll
    for (int h = 0; h < 4; ++h) {
        a_s[row * 4 + h] = aS[h];
        a_d[row * 4 + h] = aD[h];
    }
}

// ---------------------------------------------------------------------------
// gemm1: h1[N,256] (fp16) = x[N,64] @ W1[64,256]; 16 rows/block, acc[16]/thread,
// W read once per k. 2-phase 32KB LDS.
// ---------------------------------------------------------------------------
__global__ __launch_bounds__(256) void gemm1_kernel(
    const float* __restrict__ x, const float* __restrict__ W1,
    __half* __restrict__ h1, int n)
{
    __shared__ float w_s[32 * 256];          // 32 KB
    int tid = threadIdx.x;
    int row0 = blockIdx.x * 16;              // n divisible by 16
    float acc[16];
    #pragma unroll
    for (int r = 0; r < 16; ++r) acc[r] = 0.f;

    const float4* Wv = (const float4*)W1;
    for (int kk = 0; kk < 2; ++kk) {
        if (kk) __syncthreads();
        {
            float4* wv = (float4*)w_s;
            #pragma unroll
            for (int i = 0; i < 8; ++i)
                wv[tid + i * 256] = Wv[kk * 2048 + tid + i * 256];
        }
        __syncthreads();
        #pragma unroll 2
        for (int k4 = 0; k4 < 8; ++k4) {
            float4 q[16];
            #pragma unroll
            for (int r = 0; r < 16; ++r)
                q[r] = *(const float4*)(x + (size_t)(row0 + r) * 64 + kk * 32 + k4 * 4);
            #pragma unroll
            for (int e = 0; e < 4; ++e) {
                float w = w_s[(k4 * 4 + e) * 256 + tid];
                #pragma unroll
                for (int r = 0; r < 16; ++r)
                    acc[r] = fmaf(((const float*)&q[r])[e], w, acc[r]);
            }
        }
    }
    #pragma unroll
    for (int r = 0; r < 16; ++r)
        h1[(size_t)(row0 + r) * 256 + tid] = __float2half(acc[r]);
}

// ---------------------------------------------------------------------------
// gemm2: h2[N,64] (fp16) = out1r[N,256] (fp16) @ W2[256,64]; 64 rows/block
// (16/wave). Entire W2 packed fp16 in 32KB LDS; v_dot2_f32_f16 inner loop.
// ---------------------------------------------------------------------------
__global__ __launch_bounds__(256) void gemm2_kernel(
    const __half* __restrict__ xr, const float* __restrict__ W2,
    __half* __restrict__ h2, int n)
{
    __shared__ h2vec w_s[128 * 64];          // 128 k-pairs x 64 cols, 32 KB
    int tid = threadIdx.x;
    #pragma unroll 4
    for (int i = 0; i < 32; ++i) {
        int idx = tid + i * 256;
        int kp = idx >> 6, col = idx & 63;
        h2vec v;
        v[0] = (_Float16)W2[(2 * kp) * 64 + col];
        v[1] = (_Float16)W2[(2 * kp + 1) * 64 + col];
        w_s[idx] = v;
    }
    __syncthreads();
    int col = tid & 63, wv_ = tid >> 6;
    int row0 = blockIdx.x * 64 + wv_ * 16;
    float acc[16];
    #pragma unroll
    for (int r = 0; r < 16; ++r) acc[r] = 0.f;

    const float4* xb = (const float4*)(xr + (size_t)row0 * 256);  // row = 32 float4
    for (int g = 0; g < 32; ++g) {           // 4 k-pairs per group
        float4 q[16];
        #pragma unroll
        for (int r = 0; r < 16; ++r) q[r] = xb[r * 32 + g];
        #pragma unroll
        for (int e = 0; e < 4; ++e) {
            h2vec w = w_s[(g * 4 + e) * 64 + col];
            #pragma unroll
            for (int r = 0; r < 16; ++r)
                acc[r] = fdot2h(((const float*)&q[r])[e], w, acc[r]);
        }
    }
    #pragma unroll
    for (int r = 0; r < 16; ++r) {
        int row = row0 + r;
        if (row < n) h2[(size_t)row * 64 + col] = __float2half(acc[r]);
    }
}

// ---------------------------------------------------------------------------
// fused layer-1 softmax+aggregate+bias+relu + layer-2 logits.
// one block per dst node. Softmax: wave == head (exp cached in ev).
// Gather: thread owns 4 channels (uint2 = 8B) c4=tid&63, slot p=tid>>6
// (4 edges in flight); slots merged via LDS; wave 0 does epilogue.
// ---------------------------------------------------------------------------
__global__ __launch_bounds__(256) void aggr1_csr(
    const int* __restrict__ rowptr, const int* __restrict__ deg,
    const int* __restrict__ csr_src,
    const float* __restrict__ a_s, const float* __restrict__ a_d,
    const __half* __restrict__ h1, const float* __restrict__ b1,
    const float* __restrict__ wa2s, const float* __restrict__ wa2d,
    __half* __restrict__ out1r, float* __restrict__ a_s2, float* __restrict__ a_d2,
    int n)
{
    __shared__ float al[4][64];
    __shared__ int   ss[64];
    __shared__ float ev[4][128];
    __shared__ float pm[3][64][4];
    int t = blockIdx.x;
    int tid = threadIdx.x, h = tid >> 6, lane = tid & 63;
    int row0 = rowptr[t], d = deg[t];
    float adt = a_d[t * 4 + h];
    bool small = (d <= 128);

    float m = -INFINITY;
    if (small) {
        for (int i = lane; i < d; i += 64) {
            float v = lrelu(a_s[csr_src[row0 + i] * 4 + h] + adt);
            ev[h][i] = v;
            m = fmaxf(m, v);
        }
    } else {
        for (int i = lane; i < d; i += 64)
            m = fmaxf(m, lrelu(a_s[csr_src[row0 + i] * 4 + h] + adt));
    }
    #pragma unroll
    for (int off = 32; off; off >>= 1) m = fmaxf(m, __shfl_xor(m, off));

    float dsum = 0.f;
    if (small) {
        for (int i = lane; i < d; i += 64) {
            float e = __expf(ev[h][i] - m);
            ev[h][i] = e;                    // cache exp for alpha pass
            dsum += e;
        }
    } else {
        for (int i = lane; i < d; i += 64)
            dsum += __expf(lrelu(a_s[csr_src[row0 + i] * 4 + h] + adt) - m);
    }
    #pragma unroll
    for (int off = 32; off; off >>= 1) dsum += __shfl_xor(dsum, off);
    float inv = (d > 0) ? 1.f / dsum : 0.f;

    int c4 = tid & 63;           // channel quad: halves [4*c4 .. 4*c4+3]
    int p = tid >> 6;            // edge slot 0..3
    int hc = c4 >> 4;            // head of these channels
    float acc[4] = {0.f, 0.f, 0.f, 0.f};
    const uint2* hb = (const uint2*)h1;     // row = 64 uint2

    for (int c0 = 0; c0 < d; c0 += 64) {
        int i = c0 + lane;
        float alpha = 0.f;
        if (i < d) {
            if (small) alpha = ev[h][i] * inv;
            else alpha = __expf(lrelu(a_s[csr_src[row0 + i] * 4 + h] + adt) - m) * inv;
        }
        al[h][lane] = alpha;
        if (h == 0) ss[lane] = (i < d) ? csr_src[row0 + i] * 64 : 0;
        __syncthreads();
        int cl = min(64, d - c0);
        int j = p;
        for (; j + 4 < cl; j += 8) {
            float a0 = al[hc][j], a1 = al[hc][j + 4];
            uint2 g0 = hb[ss[j] + c4];
            uint2 g1 = hb[ss[j + 4] + c4];
            float f0[4], f1[4];
            cvt4(g0, f0); cvt4(g1, f1);
            #pragma unroll
            for (int q = 0; q < 4; ++q) {
                acc[q] = fmaf(a0, f0[q], acc[q]);
                acc[q] = fmaf(a1, f1[q], acc[q]);
            }
        }
        if (j < cl) {
            float a0 = al[hc][j];
            uint2 g0 = hb[ss[j] + c4];
            float f0[4];
            cvt4(g0, f0);
            #pragma unroll
            for (int q = 0; q < 4; ++q) acc[q] = fmaf(a0, f0[q], acc[q]);
        }
        __syncthreads();
    }

    if (p) {
        #pragma unroll
        for (int q = 0; q < 4; ++q) pm[p - 1][c4][q] = acc[q];
    }
    __syncthreads();
    if (p == 0) {                            // wave 0
        float4 bb = ((const float4*)b1)[c4];
        float r0 = fmaxf(acc[0] + pm[0][c4][0] + pm[1][c4][0] + pm[2][c4][0] + bb.x, 0.f);
        float r1 = fmaxf(acc[1] + pm[0][c4][1] + pm[1][c4][1] + pm[2][c4][1] + bb.y, 0.f);
        float r2 = fmaxf(acc[2] + pm[0][c4][2] + pm[1][c4][2] + pm[2][c4][2] + bb.z, 0.f);
        float r3 = fmaxf(acc[3] + pm[0][c4][3] + pm[1][c4][3] + pm[2][c4][3] + bb.w, 0.f);
        __half2 lo = __floats2half2_rn(r0, r1), hi = __floats2half2_rn(r2, r3);
        uint2 o; o.x = *(unsigned*)&lo; o.y = *(unsigned*)&hi;
        ((uint2*)out1r)[(size_t)t * 64 + c4] = o;
        float4 ws4 = ((const float4*)wa2s)[c4];
        float4 wd4 = ((const float4*)wa2d)[c4];
        float s2  = r0 * ws4.x + r1 * ws4.y + r2 * ws4.z + r3 * ws4.w;
        float d2v = r0 * wd4.x + r1 * wd4.y + r2 * wd4.z + r3 * wd4.w;
        #pragma unroll
        for (int off = 32; off; off >>= 1) {
            s2  += __shfl_down(s2, off);
            d2v += __shfl_down(d2v, off);
        }
        if (tid == 0) { a_s2[t] = s2; a_d2[t] = d2v; }
    }
}

// ---------------------------------------------------------------------------
// fused layer-2 softmax+aggregate: one wave per dst node (4/block).
// Gather: lanes 0-15 channel quads (8B), lane>>4 = edge slot (4 in flight);
// slots merged by shfl_down 32,16.
// ---------------------------------------------------------------------------
__global__ __launch_bounds__(256) void aggr2_csr(
    const int* __restrict__ rowptr, const int* __restrict__ deg,
    const int* __restrict__ csr_src,
    const float* __restrict__ a_s, const float* __restrict__ a_d,
    const __half* __restrict__ h2, const float* __restrict__ b2,
    float* __restrict__ dout, int n)
{
    __shared__ float ev2[4][128];
    __shared__ float al2[4][64];
    __shared__ int   ss2[4][64];
    int wv = threadIdx.x >> 6, lane = threadIdx.x & 63;
    int t = blockIdx.x * 4 + wv;
    if (t >= n) return;
    int row0 = rowptr[t], d = deg[t];
    float adt = a_d[t];
    bool small = (d <= 128);

    float m = -INFINITY;
    if (small) {
        for (int i = lane; i < d; i += 64) {
            float v = lrelu(a_s[csr_src[row0 + i]] + adt);
            ev2[wv][i] = v;
            m = fmaxf(m, v);
        }
    } else {
        for (int i = lane; i < d; i += 64)
            m = fmaxf(m, lrelu(a_s[csr_src[row0 + i]] + adt));
    }
    #pragma unroll
    for (int off = 32; off; off >>= 1) m = fmaxf(m, __shfl_xor(m, off));

    float dsum = 0.f;
    if (small) {
        for (int i = lane; i < d; i += 64) {
            float e = __expf(ev2[wv][i] - m);
            ev2[wv][i] = e;
            dsum += e;
        }
    } else {
        for (int i = lane; i < d; i += 64)
            dsum += __expf(lrelu(a_s[csr_src[row0 + i]] + adt) - m);
    }
    #pragma unroll
    for (int off = 32; off; off >>= 1) dsum += __shfl_xor(dsum, off);
    float inv = (d > 0) ? 1.f / dsum : 0.f;

    int c4 = lane & 15;          // channel quad (row = 16 uint2)
    int p = lane >> 4;           // edge slot 0..3
    float acc[4] = {0.f, 0.f, 0.f, 0.f};
    const uint2* hb = (const uint2*)h2;

    for (int c0 = 0; c0 < d; c0 += 64) {
        int i = c0 + lane;
        float alpha = 0.f; int so = 0;
        if (i < d) {
            int s = csr_src[row0 + i];
            so = s * 16;
            if (small) alpha = ev2[wv][i] * inv;
            else alpha = __expf(lrelu(a_s[s] + adt) - m) * inv;
        }
        al2[wv][lane] = alpha;
        ss2[wv][lane] = so;
        int cl = min(64, d - c0);
        int j = p;
        for (; j + 4 < cl; j += 8) {
            float a0 = al2[wv][j], a1 = al2[wv][j + 4];
            uint2 g0 = hb[ss2[wv][j] + c4];
            uint2 g1 = hb[ss2[wv][j + 4] + c4];
            float f0[4], f1[4];
            cvt4(g0, f0); cvt4(g1, f1);
            #pragma unroll
            for (int q = 0; q < 4; ++q) {
                acc[q] = fmaf(a0, f0[q], acc[q]);
                acc[q] = fmaf(a1, f1[q], acc[q]);
            }
        }
        if (j < cl) {
            float a0 = al2[wv][j];
            uint2 g0 = hb[ss2[wv][j] + c4];
            float f0[4];
            cvt4(g0, f0);
            #pragma unroll
            for (int q = 0; q < 4; ++q) acc[q] = fmaf(a0, f0[q], acc[q]);
        }
    }

    #pragma unroll
    for (int q = 0; q < 4; ++q) {
        acc[q] += __shfl_down(acc[q], 32);
        acc[q] += __shfl_down(acc[q], 16);
    }
    if (p == 0) {
        float4 bb = ((const float4*)b2)[c4];
        float4 o;
        o.x = acc[0] + bb.x; o.y = acc[1] + bb.y;
        o.z = acc[2] + bb.z; o.w = acc[3] + bb.w;
        ((float4*)(dout + (size_t)t * 64))[c4] = o;
    }
}

// ---------------------------------------------------------------------------
extern "C" void kernel_launch(void* const* d_in, const int* in_sizes, int n_in,
                              void* d_out, int out_size, void* d_ws, size_t ws_size,
                              hipStream_t stream)
{
    const float* x    = (const float*)d_in[0];
    const int*   ei   = (const int*)d_in[1];
    const float* W1   = (const float*)d_in[2];
    const float* as1  = (const float*)d_in[3];
    const float* ad1  = (const float*)d_in[4];
    const float* b1   = (const float*)d_in[5];
    const float* W2   = (const float*)d_in[6];
    const float* as2  = (const float*)d_in[7];
    const float* ad2  = (const float*)d_in[8];
    const float* b2   = (const float*)d_in[9];
    float* dout = (float*)d_out;

    const int n  = in_sizes[0] / H_IN;        // 50000
    const int ne = in_sizes[1] / 2;           // 800000
    const int* src = ei;
    const int* dst = ei + ne;
    const int NB = (n + 255) / 256;           // 196

    float* ws = (float*)d_ws;
    __half* h1h   = (__half*)ws;                    // n*256 halves; reused as h2
    __half* out1r = h1h + (size_t)n * 256;          // n*256 halves
    float* fbase  = ws + (size_t)n * 256;           // after the two half arrays
    float* a_s1   = fbase;                          // n*4
    float* a_d1   = a_s1   + (size_t)n * 4;         // n*4
    float* a_s2   = a_d1   + (size_t)n * 4;         // n
    float* a_d2   = a_s2   + (size_t)n;             // n
    float* wa1s   = a_d2   + (size_t)n;             // 256
    float* wa1d   = wa1s + 256;                     // 256
    float* wa2s   = wa1d + 256;                     // 256
    float* wa2d   = wa2s + 256;                     // 256
    int*   deg    = (int*)(wa2d + 256);             // n
    int*   rowptr = deg + n;                        // n
    int*   csr    = rowptr + n;                     // ne
    int*   bsum   = csr + ne;                       // NB
    int*   bpre   = bsum + NB;                      // NB
    int*   cursor = (int*)h1h;                      // n ints (dead before gemm1 writes h1)
    __half* h2h   = h1h;                            // n*64 halves (h1 dead after aggr1)

    // ---- zero + micro (W·att) ----
    zero_micro<<<NB + 1, 256, 0, stream>>>(deg, cursor, n, W1, as1, ad1,
                                           W2, as2, ad2, wa1s, wa1d, wa2s, wa2d);

    // ---- CSR build ----
    hist_kernel<<<(ne + 255) / 256, 256, 0, stream>>>(dst, deg, ne);
    block_sum<<<NB, 256, 0, stream>>>(deg, bsum, n);
    scan_bsum<<<1, 256, 0, stream>>>(bsum, bpre, NB);
    scan_rowptr<<<NB, 256, 0, stream>>>(deg, bpre, rowptr, n);
    scatter_kernel<<<(ne + 255) / 256, 256, 0, stream>>>(src, dst, rowptr, cursor, csr, ne);

    // ---- layer 1 ----
    axw1_kernel<<<NB, 256, 0, stream>>>(x, wa1s, wa1d, a_s1, a_d1, n);
    gemm1_kernel<<<n / 16, 256, 0, stream>>>(x, W1, h1h, n);
    aggr1_csr<<<n, 256, 0, stream>>>(rowptr, deg, csr, a_s1, a_d1, h1h, b1,
                                     wa2s, wa2d, out1r, a_s2, a_d2, n);

    // ---- layer 2 ----
    gemm2_kernel<<<(n + 63) / 64, 256, 0, stream>>>(out1r, W2, h2h, n);
    aggr2_csr<<<(n + 3) / 4, 256, 0, stream>>>(rowptr, deg, csr, a_s2, a_d2, h2h, b2, dout, n);
}